// Round 11
// baseline (791.922 us; speedup 1.0000x reference)
//
#include <hip/hip_runtime.h>

constexpr int NB   = 1024;  // batch
constexpr int NDIM = 32;    // x dim
constexpr int NH   = 1024;  // hidden dim
constexpr int NC   = 512;   // context dim
constexpr int NS   = 8;     // K-splits in k_gram
constexpr int KSF  = 8;     // K-splits per term in k_fgemm

constexpr float INV_SQRT2PI = 0.3989422804014327f;
constexpr float SQRT_HALF   = 0.70710678118654752f;
constexpr float SQRT_HPI    = 1.2533141373155003f;

typedef __attribute__((ext_vector_type(8))) short short8;
typedef __attribute__((ext_vector_type(4))) short short4v;
typedef __attribute__((ext_vector_type(4))) float float4v;

__device__ __forceinline__ float sp_f(float x) {
  return (x > 20.f) ? x : log1pf(expf(x));
}

__device__ __forceinline__ short f2bf(float f) {
  union { float f; unsigned u; } x; x.f = f;
  const unsigned r = x.u + 0x7fffu + ((x.u >> 16) & 1u);
  return (short)(r >> 16);
}

__device__ __forceinline__ float bf2f(short s) {
  union { unsigned u; float f; } c;
  c.u = ((unsigned)(unsigned short)s) << 16;
  return c.f;
}

__device__ __forceinline__ void async_ld16(const void* g, void* l) {
  __builtin_amdgcn_global_load_lds(
      (const __attribute__((address_space(1))) void*)g,
      (__attribute__((address_space(3))) void*)l, 16, 0, 0);
}

// ---------------- prep ----------------
__global__ __launch_bounds__(256) void k_prep(
    const float* __restrict__ Wz1, const float* __restrict__ Wz2,
    const float* __restrict__ Wzout, const float* __restrict__ Wz0,
    const float* __restrict__ Wx1, const float* __restrict__ Wx2,
    const float* __restrict__ Wc0, const float* __restrict__ Wc1,
    const float* __restrict__ Wc2, const float* __restrict__ Cc,
    short* __restrict__ S1b, short* __restrict__ S1Tb,
    short* __restrict__ S2b, short* __restrict__ S2Tb,
    short* __restrict__ Wc0b, short* __restrict__ Wc1b, short* __restrict__ Wc2b,
    short* __restrict__ Ccb, short* __restrict__ W0Tb,
    short* __restrict__ Wx1Tb, short* __restrict__ Wx2Tb,
    float* __restrict__ so)
{
  const int idx = blockIdx.x * 256 + threadIdx.x;   // 0 .. NH*NH-1
  const int i = idx >> 10, p = idx & 1023;
  const float v1 = sp_f(Wz1[idx]);
  const short b1 = f2bf(v1);
  S1b[idx] = b1; S1Tb[p * NH + i] = b1;
  const float v2 = sp_f(Wz2[idx]);
  const short b2 = f2bf(v2);
  S2b[idx] = b2; S2Tb[p * NH + i] = b2;
  if (idx < NH) so[idx] = sp_f(Wzout[idx]);
  if (idx < NH * NC) {
    Wc0b[idx] = f2bf(Wc0[idx]);
    Wc1b[idx] = f2bf(Wc1[idx]);
    Wc2b[idx] = f2bf(Wc2[idx]);
  }
  if (idx < NB * NC) Ccb[idx] = f2bf(Cc[idx]);
  if (idx < NDIM * NH) {
    const int j = idx >> 10, pp = idx & 1023;   // out [32,1024]
    W0Tb[idx]  = f2bf(Wz0[pp * NDIM + j]);
    Wx1Tb[idx] = f2bf(Wx1[pp * NDIM + j]);
    Wx2Tb[idx] = f2bf(Wx2[pp * NDIM + j]);
  }
}

// ---------------- fp32 tiled GEMM, 3 X-terms in one dispatch; z=0 fuses layer-0 act ----------------
__global__ __launch_bounds__(256) void k_gemmx(
    const float* __restrict__ A,
    const float* __restrict__ B0, const float* __restrict__ B1,
    const float* __restrict__ B2,
    float* __restrict__ C0, float* __restrict__ C1, float* __restrict__ C2,
    int ldc,
    const float* __restrict__ bz0, const float* __restrict__ bc0,
    const float* __restrict__ anb0, const float* __restrict__ anl0,
    short* __restrict__ Z0b, float* __restrict__ G0, float* __restrict__ U0)
{
  const float* Bt = (blockIdx.z == 0) ? B0 : (blockIdx.z == 1) ? B1 : B2;
  float* C        = (blockIdx.z == 0) ? C0 : (blockIdx.z == 1) ? C1 : C2;
  __shared__ float As[16][68];
  __shared__ float Bs[16][68];
  const int tid  = threadIdx.y * 16 + threadIdx.x;
  const int arow = tid >> 2;
  const int acol = (tid & 3) << 2;
  const int m0 = blockIdx.y << 6;
  const int n0 = blockIdx.x << 6;

  float acc[4][4];
#pragma unroll
  for (int i = 0; i < 4; ++i)
#pragma unroll
    for (int j = 0; j < 4; ++j) acc[i][j] = 0.f;

  const int R = m0 + arow;
  for (int k0 = 0; k0 < NDIM; k0 += 16) {
    const float4 av = *reinterpret_cast<const float4*>(&A[(size_t)R * NDIM + k0 + acol]);
    As[acol + 0][arow] = av.x; As[acol + 1][arow] = av.y;
    As[acol + 2][arow] = av.z; As[acol + 3][arow] = av.w;
    const float4 bv = *reinterpret_cast<const float4*>(&Bt[(size_t)(n0 + arow) * NDIM + k0 + acol]);
    Bs[acol + 0][arow] = bv.x; Bs[acol + 1][arow] = bv.y;
    Bs[acol + 2][arow] = bv.z; Bs[acol + 3][arow] = bv.w;
    __syncthreads();
#pragma unroll
    for (int kk = 0; kk < 16; ++kk) {
      const float4 a  = *reinterpret_cast<const float4*>(&As[kk][threadIdx.y << 2]);
      const float4 bb = *reinterpret_cast<const float4*>(&Bs[kk][threadIdx.x << 2]);
      const float am[4] = {a.x, a.y, a.z, a.w};
      const float bn[4] = {bb.x, bb.y, bb.z, bb.w};
#pragma unroll
      for (int i2 = 0; i2 < 4; ++i2)
#pragma unroll
        for (int j2 = 0; j2 < 4; ++j2)
          acc[i2][j2] = fmaf(am[i2], bn[j2], acc[i2][j2]);
    }
    __syncthreads();
  }
#pragma unroll
  for (int i2 = 0; i2 < 4; ++i2) {
    const int row = m0 + (threadIdx.y << 2) + i2;
    const int col = n0 + (threadIdx.x << 2);
    float* cp = &C[(size_t)row * ldc + col];
    const float4 cur = *reinterpret_cast<const float4*>(cp);
    float o[4];
    o[0] = acc[i2][0] + cur.x; o[1] = acc[i2][1] + cur.y;
    o[2] = acc[i2][2] + cur.z; o[3] = acc[i2][3] + cur.w;
    if (blockIdx.z == 0) {
      // fused layer-0 activation: a = (h + bias)*el
      short4v zb;
      float4 g4, u4;
      float gg[4], uu[4];
#pragma unroll
      for (int e = 0; e < 4; ++e) {
        const int cc = col + e;
        const float bias = bz0[cc] + bc0[cc] + anb0[cc];
        const float el = expf(anl0[cc]);
        const float a = (o[e] + bias) * el;
        const float pdf = expf(-0.5f * a * a);
        const float er = erff(a * SQRT_HALF);
        zb[e] = f2bf((SQRT_HPI * a * er + pdf + SQRT_HPI * a) * INV_SQRT2PI);
        gg[e] = 0.5f * (1.f + er) * el;
        uu[e] = pdf * INV_SQRT2PI * el * el;
      }
      const size_t oi = (size_t)row * NH + col;
      *(short4v*)&Z0b[oi] = zb;
      g4.x = gg[0]; g4.y = gg[1]; g4.z = gg[2]; g4.w = gg[3];
      u4.x = uu[0]; u4.y = uu[1]; u4.z = uu[2]; u4.w = uu[3];
      *(float4*)&G0[oi] = g4;
      *(float4*)&U0[oi] = u4;
    } else {
      float4 ov;
      ov.x = o[0]; ov.y = o[1]; ov.z = o[2]; ov.w = o[3];
      *reinterpret_cast<float4*>(cp) = ov;
    }
  }
}

// ---------------- bf16 MFMA GEMM, 128x128 tile, fp32 out (c-path), transposed tiles ----------------
__global__ __launch_bounds__(256) void k_m128(
    const short* __restrict__ A, const short* __restrict__ Bt,
    float* __restrict__ C, float scale, int K, int ldc)
{
  __shared__ short As[128 * 32];
  __shared__ short Bs[128 * 32];
  const int tid  = threadIdx.x;
  const int wave = tid >> 6, lane = tid & 63;
  const int m0 = blockIdx.x << 7, n0 = blockIdx.y << 7;   // XCD swizzle
  const int wm = (wave >> 1) << 6, wn = (wave & 1) << 6;
  const int qd = lane >> 4, md = lane & 15;
  const int sr = lane >> 2;
  const int sc = (lane & 3) << 3;

  float4v acc[4][4];
#pragma unroll
  for (int i = 0; i < 4; ++i)
#pragma unroll
    for (int j = 0; j < 4; ++j) acc[i][j] = (float4v)(0.f);

  for (int k0 = 0; k0 < K; k0 += 32) {
#pragma unroll
    for (int i = 0; i < 2; ++i) {
      const int ch  = wave * 2 + i;
      const int row = ch * 16 + sr;
      async_ld16(&A [(size_t)(m0 + row) * K + k0 + sc], &As[ch * 512]);
      async_ld16(&Bt[(size_t)(n0 + row) * K + k0 + sc], &Bs[ch * 512]);
    }
    __syncthreads();
    short8 af[4], bfr[4];
#pragma unroll
    for (int t = 0; t < 4; ++t) {
      af[t]  = *(const short8*)&As[(wm + t * 16 + md) * 32 + qd * 8];
      bfr[t] = *(const short8*)&Bs[(wn + t * 16 + md) * 32 + qd * 8];
    }
#pragma unroll
    for (int i = 0; i < 4; ++i)
#pragma unroll
      for (int j = 0; j < 4; ++j)
        acc[i][j] = __builtin_amdgcn_mfma_f32_16x16x32_bf16(bfr[j], af[i], acc[i][j], 0, 0, 0);
    __syncthreads();
  }

#pragma unroll
  for (int i = 0; i < 4; ++i) {
    const int rowg = m0 + wm + i * 16 + md;
#pragma unroll
    for (int j = 0; j < 4; ++j) {
      const int colb = n0 + wn + j * 16 + (qd << 2);
      float4 o;
      o.x = acc[i][j][0] * scale; o.y = acc[i][j][1] * scale;
      o.z = acc[i][j][2] * scale; o.w = acc[i][j][3] * scale;
      *reinterpret_cast<float4*>(&C[(size_t)rowg * ldc + colb]) = o;
    }
  }
}

// ---------------- bf16 MFMA GEMM, 128x64 tile (Jacobian GEMMs) ----------------
// A via async LDS; B direct global->VGPR (L2-resident slice). Transposed tiles.
// grid (CB*32/128, NH/64) — x = M-block (XCD locality on A). dvec PRE-SQRT'd.
// EPI 1: o1 = bf16((acc*scale + WxT) * dvec)                      [Q2]
// EPI 2: o1 = ..., o2 = bf16((acc*scale + WxT) * gvec)            [Q1, A2]
template<int EPI>
__global__ __launch_bounds__(256) void k_mgemm(
    const short* __restrict__ A, const short* __restrict__ Bt,
    short* __restrict__ o1, short* __restrict__ o2,
    const float* __restrict__ gvec, const float* __restrict__ dvec,
    const short* __restrict__ wepiT,
    float scale, int K, int b0)
{
  __shared__ short As[128 * 32];   // 8 KB (A only)
  const int tid  = threadIdx.x;
  const int wave = tid >> 6, lane = tid & 63;
  const int m0 = blockIdx.x << 7, n0 = blockIdx.y << 6;   // 128 x 64 tile
  const int wm = (wave >> 1) << 6, wn = (wave & 1) << 5;  // wave: 64 x 32
  const int qd = lane >> 4, md = lane & 15;
  const int sr = lane >> 2;
  const int sc = (lane & 3) << 3;

  float4v acc[4][2];
#pragma unroll
  for (int i = 0; i < 4; ++i)
#pragma unroll
    for (int j = 0; j < 2; ++j) acc[i][j] = (float4v)(0.f);

  for (int k0 = 0; k0 < K; k0 += 32) {
    // stage A: 8 chunks of 16 rows, 2 per wave
#pragma unroll
    for (int i = 0; i < 2; ++i) {
      const int ch = wave * 2 + i;
      async_ld16(&A[(size_t)(m0 + ch * 16 + sr) * K + k0 + sc], &As[ch * 512]);
    }
    // B frags direct from global (completes under the A-drain)
    short8 bfr[2];
#pragma unroll
    for (int t = 0; t < 2; ++t)
      bfr[t] = *(const short8*)&Bt[(size_t)(n0 + wn + t * 16 + md) * K + k0 + qd * 8];
    __syncthreads();
    short8 af[4];
#pragma unroll
    for (int t = 0; t < 4; ++t)
      af[t] = *(const short8*)&As[(wm + t * 16 + md) * 32 + qd * 8];
#pragma unroll
    for (int i = 0; i < 4; ++i)
#pragma unroll
      for (int j = 0; j < 2; ++j)
        acc[i][j] = __builtin_amdgcn_mfma_f32_16x16x32_bf16(bfr[j], af[i], acc[i][j], 0, 0, 0);
    __syncthreads();
  }

  // transposed: lane holds orig row = m0+wm+i*16+md, cols = n0+wn+j*16+qd*4..+3
  const int bbase = b0 + ((m0 + wm) >> 5);
  const size_t bNH0 = (size_t)bbase * NH, bNH1 = bNH0 + NH;
  float4 dqA[2], dqB[2], ggA[2], ggB[2];
#pragma unroll
  for (int j = 0; j < 2; ++j) {
    const int colb = n0 + wn + j * 16 + (qd << 2);
    dqA[j] = *(const float4*)&dvec[bNH0 + colb];
    dqB[j] = *(const float4*)&dvec[bNH1 + colb];
    if constexpr (EPI == 2) {
      ggA[j] = *(const float4*)&gvec[bNH0 + colb];
      ggB[j] = *(const float4*)&gvec[bNH1 + colb];
    }
  }
#pragma unroll
  for (int i = 0; i < 4; ++i) {
    const int rowg = m0 + wm + i * 16 + md;
    const int j2 = rowg & 31;
#pragma unroll
    for (int j = 0; j < 2; ++j) {
      const int colb = n0 + wn + j * 16 + (qd << 2);
      const short4v wq = *(const short4v*)&wepiT[(size_t)j2 * NH + colb];
      const float4 dq = (i < 2) ? dqA[j] : dqB[j];
      const float dqv[4] = {dq.x, dq.y, dq.z, dq.w};
      float v[4];
      short4v o1v;
#pragma unroll
      for (int r = 0; r < 4; ++r) {
        v[r] = acc[i][j][r] * scale + bf2f(wq[r]);
        o1v[r] = f2bf(v[r] * dqv[r]);
      }
      *(short4v*)&o1[(size_t)rowg * NH + colb] = o1v;
      if constexpr (EPI == 2) {
        const float4 gg = (i < 2) ? ggA[j] : ggB[j];
        const float ggv[4] = {gg.x, gg.y, gg.z, gg.w};
        short4v o2v;
#pragma unroll
        for (int r = 0; r < 4; ++r) o2v[r] = f2bf(v[r] * ggv[r]);
        *(short4v*)&o2[(size_t)rowg * NH + colb] = o2v;
      }
    }
  }
}

// ---------------- bf16 MFMA GEMM, 64x64 tile, K-split partials (z=2, forward) ----------------
__global__ __launch_bounds__(256) void k_mgemm64s(
    const short* __restrict__ A, const short* __restrict__ Bt,
    float* __restrict__ Cpart)
{
  __shared__ short As[64 * 32];
  __shared__ short Bs[64 * 32];
  const int tid  = threadIdx.x;
  const int wave = tid >> 6, lane = tid & 63;
  const int m0 = blockIdx.x << 6, n0 = blockIdx.y << 6;   // XCD swizzle
  const int kb = blockIdx.z << 9;                          // 0 or 512
  const int wm = (wave >> 1) << 5, wn = (wave & 1) << 5;
  const int qd = lane >> 4, md = lane & 15;
  const int sr = lane >> 2;
  const int sc = (lane & 3) << 3;

  float4v acc[2][2];
#pragma unroll
  for (int i = 0; i < 2; ++i)
#pragma unroll
    for (int j = 0; j < 2; ++j) acc[i][j] = (float4v)(0.f);

  for (int k0 = kb; k0 < kb + 512; k0 += 32) {
    const int row = wave * 16 + sr;
    async_ld16(&A [(size_t)(m0 + row) * NH + k0 + sc], &As[wave * 512]);
    async_ld16(&Bt[(size_t)(n0 + row) * NH + k0 + sc], &Bs[wave * 512]);
    __syncthreads();
    short8 af[2], bfr[2];
#pragma unroll
    for (int t = 0; t < 2; ++t) {
      af[t]  = *(const short8*)&As[(wm + t * 16 + md) * 32 + qd * 8];
      bfr[t] = *(const short8*)&Bs[(wn + t * 16 + md) * 32 + qd * 8];
    }
#pragma unroll
    for (int i = 0; i < 2; ++i)
#pragma unroll
      for (int j = 0; j < 2; ++j)
        acc[i][j] = __builtin_amdgcn_mfma_f32_16x16x32_bf16(bfr[j], af[i], acc[i][j], 0, 0, 0);
    __syncthreads();
  }

  float* out = Cpart + (size_t)blockIdx.z * NB * NH;
#pragma unroll
  for (int i = 0; i < 2; ++i) {
    const int rowg = m0 + wm + i * 16 + md;
#pragma unroll
    for (int j = 0; j < 2; ++j) {
      const int colb = n0 + wn + j * 16 + (qd << 2);
      float4 o;
      o.x = acc[i][j][0]; o.y = acc[i][j][1];
      o.z = acc[i][j][2]; o.w = acc[i][j][3];
      *reinterpret_cast<float4*>(&out[(size_t)rowg * NH + colb]) = o;
    }
  }
}

// ---------------- bf16 MFMA GEMM, 64x64 tile, fused backward epilogues (unsplit) ----------------
// FEPI 3 (bw1): t=acc*scale; ob=bf16(t*auxA), of1=sqrt(max(t*auxB,0))   [E1b, SD1]
// FEPI 4 (bw0): t=acc*scale; ob=bf16(t*auxA), of1=t*auxB               [GT0b, D0]
template<int FEPI>
__global__ __launch_bounds__(256) void k_mgemm64f(
    const short* __restrict__ A, const short* __restrict__ Bt,
    const float* __restrict__ auxA, const float* __restrict__ auxB,
    short* __restrict__ ob, float* __restrict__ of1,
    float scale)
{
  __shared__ short As[64 * 32];
  __shared__ short Bs[64 * 32];
  const int tid  = threadIdx.x;
  const int wave = tid >> 6, lane = tid & 63;
  const int m0 = blockIdx.x << 6, n0 = blockIdx.y << 6;
  const int wm = (wave >> 1) << 5, wn = (wave & 1) << 5;
  const int qd = lane >> 4, md = lane & 15;
  const int sr = lane >> 2;
  const int sc = (lane & 3) << 3;

  float4v acc[2][2];
#pragma unroll
  for (int i = 0; i < 2; ++i)
#pragma unroll
    for (int j = 0; j < 2; ++j) acc[i][j] = (float4v)(0.f);

  for (int k0 = 0; k0 < NH; k0 += 32) {
    const int row = wave * 16 + sr;
    async_ld16(&A [(size_t)(m0 + row) * NH + k0 + sc], &As[wave * 512]);
    async_ld16(&Bt[(size_t)(n0 + row) * NH + k0 + sc], &Bs[wave * 512]);
    __syncthreads();
    short8 af[2], bfr[2];
#pragma unroll
    for (int t = 0; t < 2; ++t) {
      af[t]  = *(const short8*)&As[(wm + t * 16 + md) * 32 + qd * 8];
      bfr[t] = *(const short8*)&Bs[(wn + t * 16 + md) * 32 + qd * 8];
    }
#pragma unroll
    for (int i = 0; i < 2; ++i)
#pragma unroll
      for (int j = 0; j < 2; ++j)
        acc[i][j] = __builtin_amdgcn_mfma_f32_16x16x32_bf16(bfr[j], af[i], acc[i][j], 0, 0, 0);
    __syncthreads();
  }

#pragma unroll
  for (int i = 0; i < 2; ++i) {
    const int rowg = m0 + wm + i * 16 + md;
#pragma unroll
    for (int j = 0; j < 2; ++j) {
      const int colb = n0 + wn + j * 16 + (qd << 2);
      const size_t oi = (size_t)rowg * NH + colb;
      const float4 g4 = *(const float4*)&auxA[oi];
      const float4 u4 = *(const float4*)&auxB[oi];
      const float gv[4] = {g4.x, g4.y, g4.z, g4.w};
      const float uv[4] = {u4.x, u4.y, u4.z, u4.w};
      short4v eb;
      float sd[4];
#pragma unroll
      for (int r = 0; r < 4; ++r) {
        const float t = acc[i][j][r] * scale;
        eb[r] = f2bf(t * gv[r]);
        if constexpr (FEPI == 3) sd[r] = sqrtf(fmaxf(t * uv[r], 0.f));
        else                     sd[r] = t * uv[r];
      }
      *(short4v*)&ob[oi] = eb;
      float4 s4; s4.x = sd[0]; s4.y = sd[1]; s4.z = sd[2]; s4.w = sd[3];
      *(float4*)&of1[oi] = s4;
    }
  }
}

// ---------------- activation (layer 1): sum HP halves, writes Zbf, G, U ----------------
__global__ __launch_bounds__(256) void k_act(
    const float* __restrict__ HP2, const float* __restrict__ HPC_l,
    const float* __restrict__ bA, const float* __restrict__ bB,
    const float* __restrict__ bC,
    const float* __restrict__ anb, const float* __restrict__ anl,
    short* __restrict__ Zbf, float* __restrict__ G, float* __restrict__ U,
    float scale)
{
  const int idx = blockIdx.x * 256 + threadIdx.x;
  const int i = idx & 1023;
  const float bias = bA[i] + bB[i] + bC[i] + anb[i];
  const float el = expf(anl[i]);
  const float hc = HPC_l[(size_t)(idx >> 10) * (3 * NH) + i];
  const float hp = (HP2[idx] + HP2[(size_t)NB * NH + idx]) * scale;
  const float a = (hp + hc + bias) * el;
  const float pdf = expf(-0.5f * a * a);
  const float er = erff(a * SQRT_HALF);
  Zbf[idx] = f2bf((SQRT_HPI * a * er + pdf + SQRT_HPI * a) * INV_SQRT2PI);
  G[idx] = 0.5f * (1.f + er) * el;
  U[idx] = pdf * INV_SQRT2PI * el * el;
}

// ---------------- activation (layer 2): SD2 = sqrt(t2*u2), D2g bf16 ----------------
__global__ __launch_bounds__(256) void k_act2(
    const float* __restrict__ HP2, const float* __restrict__ HPC_l,
    const float* __restrict__ bA, const float* __restrict__ bB,
    const float* __restrict__ bC,
    const float* __restrict__ anb, const float* __restrict__ anl,
    const float* __restrict__ so,
    float* __restrict__ SD2, short* __restrict__ D2gbf, float scale)
{
  const int idx = blockIdx.x * 256 + threadIdx.x;
  const int i = idx & 1023;
  const float bias = bA[i] + bB[i] + bC[i] + anb[i];
  const float el = expf(anl[i]);
  const float hc = HPC_l[(size_t)(idx >> 10) * (3 * NH) + i];
  const float hp = (HP2[idx] + HP2[(size_t)NB * NH + idx]) * scale;
  const float a = (hp + hc + bias) * el;
  const float pdf = expf(-0.5f * a * a);
  const float er = erff(a * SQRT_HALF);
  const float g = 0.5f * (1.f + er) * el;
  const float u = pdf * INV_SQRT2PI * el * el;
  const float t2 = so[i] * (1.f / NH);
  SD2[idx] = sqrtf(fmaxf(t2 * u, 0.f));
  D2gbf[idx] = f2bf(t2 * g);
}

// ---------------- Ah1[r,p] = bf16(G0[b,p] * W0T[j,p]) (coalesced) ----------------
__global__ __launch_bounds__(256) void k_scale0(
    const float* __restrict__ G0, const short* __restrict__ W0Tb,
    short* __restrict__ Ah1, int b0)
{
  const int idx = blockIdx.x * 256 + threadIdx.x;
  const int p = idx & 1023, r = idx >> 10;
  const int b = b0 + (r >> 5), j = r & 31;
  Ah1[idx] = f2bf(G0[(size_t)b * NH + p] * bf2f(W0Tb[(size_t)j * NH + p]));
}

// ---------------- f-GEMM: MFMA partials of [NB,NH]@[NH,32] per term/k-split ----------------
__global__ __launch_bounds__(256) void k_fgemm(
    const short* __restrict__ A0, const short* __restrict__ A1,
    const short* __restrict__ A2,
    const short* __restrict__ W0T, const short* __restrict__ W1T,
    const short* __restrict__ W2T,
    float* __restrict__ partF)
{
  const int mb = blockIdx.x;
  const int ks = blockIdx.y;
  const int term = blockIdx.z;
  const short* A  = (term == 0) ? A0 : (term == 1) ? A1 : A2;
  const short* WT = (term == 0) ? W0T : (term == 1) ? W1T : W2T;
  const int wave = threadIdx.x >> 6, lane = threadIdx.x & 63;
  const int qd = lane >> 4, md = lane & 15;
  const int m0 = mb * 128 + wave * 32;
  const int kbeg = ks * (NH / KSF);

  float4v acc[2][2];
#pragma unroll
  for (int i = 0; i < 2; ++i)
#pragma unroll
    for (int j = 0; j < 2; ++j) acc[i][j] = (float4v)(0.f);

  for (int k0 = kbeg; k0 < kbeg + NH / KSF; k0 += 32) {
    const int kk = k0 + qd * 8;
    short8 af[2], bfr[2];
    af[0]  = *(const short8*)&A[(size_t)(m0 + md) * NH + kk];
    af[1]  = *(const short8*)&A[(size_t)(m0 + 16 + md) * NH + kk];
    bfr[0] = *(const short8*)&WT[(size_t)md * NH + kk];
    bfr[1] = *(const short8*)&WT[(size_t)(16 + md) * NH + kk];
#pragma unroll
    for (int i = 0; i < 2; ++i)
#pragma unroll
      for (int j = 0; j < 2; ++j)
        acc[i][j] = __builtin_amdgcn_mfma_f32_16x16x32_bf16(af[i], bfr[j], acc[i][j], 0, 0, 0);
  }

  float* out = &partF[(size_t)(term * KSF + ks) * NB * 32];
#pragma unroll
  for (int i = 0; i < 2; ++i)
#pragma unroll
    for (int j = 0; j < 2; ++j)
#pragma unroll
      for (int r = 0; r < 4; ++r) {
        const int row = m0 + i * 16 + qd * 4 + r;
        const int col = j * 16 + md;
        out[(size_t)row * 32 + col] = acc[i][j][r];
      }
}

// ---------------- reduce f partials + epilogue ----------------
__global__ __launch_bounds__(256) void k_fred(
    const float* __restrict__ partF, const float* __restrict__ X,
    const float* __restrict__ Wxout,
    const float* __restrict__ w0p, const float* __restrict__ w1p,
    float* __restrict__ outF)
{
  const int e = blockIdx.x * 256 + threadIdx.x;
  float s = 0.f;
#pragma unroll
  for (int p = 0; p < 3 * KSF; ++p) s += partF[(size_t)p * NB * 32 + e];
  const float spw0 = sp_f(w0p[0]);
  const float spw1 = sp_f(w1p[0]);
  outF[e] = spw1 * (s + Wxout[e & 31]) + spw0 * X[e];
}

// ---------------- K-split per-sample Gram partials ----------------
__global__ __launch_bounds__(256) void k_gram(
    const short* __restrict__ Q1, const short* __restrict__ Q2,
    const short* __restrict__ W0T, const float* __restrict__ D0,
    float* __restrict__ partH, int b0)
{
  const int ns = blockIdx.x, bl = blockIdx.y;
  const int b = b0 + bl;
  const int wave = threadIdx.x >> 6, lane = threadIdx.x & 63;
  const int wm = (wave >> 1) << 4, wn = (wave & 1) << 4;
  const int qd = lane >> 4, md = lane & 15;
  const int kbeg = ns << 7;
  const size_t rb = (size_t)bl * 32 * NH;

  float4v acc = (float4v)(0.f);

  for (int k0 = kbeg; k0 < kbeg + 128; k0 += 32) {
    const int kk = k0 + qd * 8;
    const short8 ar = *(const short8*)&W0T[(size_t)(wm + md) * NH + kk];
    float dd[8];
    *(float4*)&dd[0] = *(const float4*)&D0[(size_t)b * NH + kk];
    *(float4*)&dd[4] = *(const float4*)&D0[(size_t)b * NH + kk + 4];
    short8 af;
#pragma unroll
    for (int e = 0; e < 8; ++e) af[e] = f2bf(bf2f(ar[e]) * dd[e]);
    const short8 bfr = *(const short8*)&W0T[(size_t)(wn + md) * NH + kk];
    acc = __builtin_amdgcn_mfma_f32_16x16x32_bf16(af, bfr, acc, 0, 0, 0);
  }
#pragma unroll
  for (int l = 0; l < 2; ++l) {
    const short* Q = (l == 0) ? Q1 : Q2;
    for (int k0 = kbeg; k0 < kbeg + 128; k0 += 32) {
      const int kk = k0 + qd * 8;
      const short8 af  = *(const short8*)&Q[rb + (size_t)(wm + md) * NH + kk];
      const short8 bfr = *(const short8*)&Q[rb + (size_t)(wn + md) * NH + kk];
      acc = __builtin_amdgcn_mfma_f32_16x16x32_bf16(af, bfr, acc, 0, 0, 0);
    }
  }

  float* out = &partH[((size_t)bl * NS + ns) * 1024];
#pragma unroll
  for (int r = 0; r < 4; ++r)
    out[(wm + qd * 4 + r) * 32 + (wn + md)] = acc[r];
}

// ---------------- reduce partials + Cholesky logdet ----------------
__global__ __launch_bounds__(256) void k_gram2(
    const float* __restrict__ partH,
    const float* __restrict__ w0p, const float* __restrict__ w1p,
    float* __restrict__ outLD, int b0)
{
  const int bl = blockIdx.x, b = b0 + bl, tid = threadIdx.x;
  __shared__ float sH[32][33];
  __shared__ float sred[32];
  const float spw0 = sp_f(w0p[0]);
  const float spw1 = sp_f(w1p[0]);
  const float* base = &partH[(size_t)bl * NS * 1024];
#pragma unroll
  for (int r = 0; r < 4; ++r) {
    const int e = r * 256 + tid;
    float s = 0.f;
#pragma unroll
    for (int ns = 0; ns < NS; ++ns) s += base[ns * 1024 + e];
    float h = s * spw1;
    const int row = e >> 5, col = e & 31;
    if (row == col) h += spw0;
    sH[row][col] = h;
  }
  __syncthreads();

  float ldacc = 0.f;
  for (int c = 0; c < 32; ++c) {
    if (tid >= c && tid < 32) {
      float s = sH[tid][c];
      for (int m = 0; m < c; ++m) s -= sH[tid][m] * sH[c][m];
      sred[tid] = s;
    }
    __syncthreads();
    const float sc = sred[c];
    if (tid >= c && tid < 32) {
      const float lcc = sqrtf(sc);
      sH[tid][c] = (tid == c) ? lcc : sred[tid] / lcc;
    }
    ldacc += logf(sc);
    __syncthreads();
  }
  if (tid == 0) outLD[b] = ldacc;
}

// ---------------- launcher ----------------
extern "C" void kernel_launch(void* const* d_in, const int* in_sizes, int n_in,
                              void* d_out, int out_size, void* d_ws, size_t ws_size,
                              hipStream_t stream)
{
  const float* X    = (const float*)d_in[0];
  const float* Cc   = (const float*)d_in[1];
  const float* w0   = (const float*)d_in[2];
  const float* w1   = (const float*)d_in[3];
  const float* Wz0w = (const float*)d_in[4];
  const float* Wz0b = (const float*)d_in[5];
  const float* Wc0w = (const float*)d_in[6];
  const float* Wc0b = (const float*)d_in[7];
  const float* an0b = (const float*)d_in[8];
  const float* an0l = (const float*)d_in[9];
  const float* Wz1w = (const float*)d_in[10];
  const float* Wz1b = (const float*)d_in[11];
  const float* Wx1w = (const float*)d_in[12];
  const float* Wx1b = (const float*)d_in[13];
  const float* Wc1w = (const float*)d_in[14];
  const float* Wc1b = (const float*)d_in[15];
  const float* an1b = (const float*)d_in[16];
  const float* an1l = (const float*)d_in[17];
  const float* Wz2w = (const float*)d_in[18];
  const float* Wz2b = (const float*)d_in[19];
  const float* Wx2w = (const float*)d_in[20];
  const float* Wx2b = (const float*)d_in[21];
  const float* Wc2w = (const float*)d_in[22];
  const float* Wc2b = (const float*)d_in[23];
  const float* an2b = (const float*)d_in[24];
  const float* an2l = (const float*)d_in[25];
  const float* Wzoutw = (const float*)d_in[26];
  const float* Wxoutw = (const float*)d_in[27];
  // d_in[28] (Wcout_w): constant in x -> no grad/Hessian contribution.

  float* ws = (float*)d_ws;
  size_t off = 0;
  auto alloc = [&](size_t n) {
    float* p = ws + off; off += (n + 3) & ~(size_t)3; return p;
  };
  const size_t HH = (size_t)NH * NH;
  const size_t BH = (size_t)NB * NH;

  short* S1b  = (short*)alloc(HH / 2);
  short* S2b  = (short*)alloc(HH / 2);
  short* S1Tb = (short*)alloc(HH / 2);
  short* S2Tb = (short*)alloc(HH / 2);
  short* Wc0bb = (short*)alloc((size_t)NH * NC / 2);
  short* Wc1bb = (short*)alloc((size_t)NH * NC / 2);
  short* Wc2bb = (short*)alloc((size_t)NH * NC / 2);
  short* Ccb  = (short*)alloc((size_t)NB * NC / 2);
  short* W0Tb = (short*)alloc((size_t)NDIM * NH / 2);
  short* Wx1Tb = (short*)alloc((size_t)NDIM * NH / 2);
  short* Wx2Tb = (short*)alloc((size_t)NDIM * NH / 2);
  float* so   = alloc(NH);
  float* HP2  = alloc(2 * BH);                // K-split GEMM partials
  float* HPC  = alloc((size_t)NB * 3 * NH);   // c-path + X-terms [NB, 3*NH]
  short* Z0b  = (short*)alloc(BH / 2);
  short* Z1b  = (short*)alloc(BH / 2);
  float* G0   = alloc(BH);
  float* U0   = alloc(BH);
  float* G1   = alloc(BH);
  float* U1   = alloc(BH);
  float* SD2  = alloc(BH);
  short* D2gb = (short*)alloc(BH / 2);
  short* E1b  = (short*)alloc(BH / 2);
  float* SD1  = alloc(BH);
  float* D0   = alloc(BH);
  short* GT0b = (short*)alloc(BH / 2);
  float* partF = alloc((size_t)3 * KSF * NB * 32);

  // chunk buffers: Ah1, A2, Q1 (bf16); Q2 aliases Ah1 (dead after GEMM1)
  const size_t avail_f = ws_size / sizeof(float);
  int CB = 32;
  const int cands[6] = {1024, 512, 256, 128, 64, 32};
  for (int ci = 0; ci < 6; ++ci) {
    const size_t need = off + 3 * ((size_t)cands[ci] * 32 * NH / 2 + 4)
                      + (size_t)cands[ci] * NS * 1024 + 64;
    if (need <= avail_f) { CB = cands[ci]; break; }
  }
  const size_t chunk_sh = (size_t)CB * 32 * NH;
  short* Ah1 = (short*)alloc(chunk_sh / 2);
  short* A2b = (short*)alloc(chunk_sh / 2);
  short* Q1b = (short*)alloc(chunk_sh / 2);
  short* Q2b = Ah1;
  float* partH = alloc((size_t)CB * NS * 1024);

  float* outF  = (float*)d_out;
  float* outLD = (float*)d_out + NB * NDIM;

  const dim3 blk2(16, 16);
  const dim3 gridXz(16, NB / 64, 3);        // fused X-terms (+ act0 in z=0)
  const dim3 gridE(NB * NH / 256);
  const dim3 grid64s(NB / 64, NH / 64, 2);  // K-split 64-tile mfma (512 blocks)
  const dim3 grid64u(NB / 64, NH / 64);     // unsplit fused-backward 64-tile
  const dim3 gridC(NB / 128, 3 * NH / 128); // fused c-GEMM
  const float invH = 1.0f / (float)NH;

  k_prep<<<dim3(HH / 256), dim3(256), 0, stream>>>(
      Wz1w, Wz2w, Wzoutw, Wz0w, Wx1w, Wx2w, Wc0w, Wc1w, Wc2w, Cc,
      S1b, S1Tb, S2b, S2Tb, Wc0bb, Wc1bb, Wc2bb, Ccb, W0Tb, Wx1Tb, Wx2Tb, so);

  // HPC = c-path (bf16 MFMA), then X-terms (fp32) with fused layer-0 activation (z=0)
  k_m128<<<gridC, dim3(256), 0, stream>>>(Ccb, Wc0bb, HPC, 1.f, NC, 3 * NH);
  k_gemmx<<<gridXz, blk2, 0, stream>>>(X, Wz0w, Wx1w, Wx2w,
                                       HPC + 0 * NH, HPC + 1 * NH, HPC + 2 * NH, 3 * NH,
                                       Wz0b, Wc0b, an0b, an0l, Z0b, G0, U0);

  // layer 1
  k_mgemm64s<<<grid64s, dim3(256), 0, stream>>>(Z0b, S1b, HP2);
  k_act<<<gridE, dim3(256), 0, stream>>>(HP2, HPC + 1 * NH, Wz1b, Wx1b, Wc1b,
                                         an1b, an1l, Z1b, G1, U1, invH);
  // layer 2
  k_mgemm64s<<<grid64s, dim3(256), 0, stream>>>(Z1b, S2b, HP2);
  k_act2<<<gridE, dim3(256), 0, stream>>>(HP2, HPC + 2 * NH, Wz2b, Wx2b, Wc2b,
                                          an2b, an2l, so, SD2, D2gb, invH);
  // backward sensitivities (fused epilogues, unsplit)
  k_mgemm64f<3><<<grid64u, dim3(256), 0, stream>>>(D2gb, S2Tb, G1, U1, E1b, SD1, invH);
  k_mgemm64f<4><<<grid64u, dim3(256), 0, stream>>>(E1b, S1Tb, G0, U0, GT0b, D0, invH);

  // f (grad) via MFMA partials + reduce
  k_fgemm<<<dim3(8, KSF, 3), dim3(256), 0, stream>>>(
      GT0b, E1b, D2gb, W0Tb, Wx1Tb, Wx2Tb, partF);
  k_fred<<<dim3(NB * 32 / 256), dim3(256), 0, stream>>>(
      partF, X, Wxoutw, w0, w1, outF);

  // Jacobian propagation + K-split Gram + Cholesky, chunked over samples
  const dim3 gridJ(CB * 32 / 128, NH / 64);    // 128x64 tile (x = M-block, XCD swizzle)
  const dim3 gridS((size_t)CB * 32 * NH / 256);
  const dim3 gridG(NS, CB);
  for (int b0 = 0; b0 < NB; b0 += CB) {
    k_scale0<<<gridS, dim3(256), 0, stream>>>(G0, W0Tb, Ah1, b0);
    k_mgemm<2><<<gridJ, dim3(256), 0, stream>>>(Ah1, S1b, Q1b, A2b,
                                                G1, SD1, Wx1Tb, invH, NH, b0);
    k_mgemm<1><<<gridJ, dim3(256), 0, stream>>>(A2b, S2b, Q2b, nullptr,
                                                nullptr, SD2, Wx2Tb, invH, NH, b0);
    k_gram<<<gridG, dim3(256), 0, stream>>>(Q1b, Q2b, W0Tb, D0, partH, b0);
    k_gram2<<<dim3(CB), dim3(256), 0, stream>>>(partH, w0, w1, outLD, b0);
  }
}

// Round 12
// 679.703 us; speedup vs baseline: 1.1651x; 1.1651x over previous
//
#include <hip/hip_runtime.h>

constexpr int NB   = 1024;  // batch
constexpr int NDIM = 32;    // x dim
constexpr int NH   = 1024;  // hidden dim
constexpr int NC   = 512;   // context dim
constexpr int NS   = 8;     // K-splits in k_gram
constexpr int KSF  = 8;     // K-splits per term in k_fgemm

constexpr float INV_SQRT2PI = 0.3989422804014327f;
constexpr float SQRT_HALF   = 0.70710678118654752f;
constexpr float SQRT_HPI    = 1.2533141373155003f;

typedef __attribute__((ext_vector_type(8))) short short8;
typedef __attribute__((ext_vector_type(4))) short short4v;
typedef __attribute__((ext_vector_type(4))) float float4v;

__device__ __forceinline__ float sp_f(float x) {
  return (x > 20.f) ? x : log1pf(expf(x));
}

__device__ __forceinline__ short f2bf(float f) {
  union { float f; unsigned u; } x; x.f = f;
  const unsigned r = x.u + 0x7fffu + ((x.u >> 16) & 1u);
  return (short)(r >> 16);
}

__device__ __forceinline__ float bf2f(short s) {
  union { unsigned u; float f; } c;
  c.u = ((unsigned)(unsigned short)s) << 16;
  return c.f;
}

__device__ __forceinline__ void async_ld16(const void* g, void* l) {
  __builtin_amdgcn_global_load_lds(
      (const __attribute__((address_space(1))) void*)g,
      (__attribute__((address_space(3))) void*)l, 16, 0, 0);
}

// ---------------- prep ----------------
__global__ __launch_bounds__(256) void k_prep(
    const float* __restrict__ Wz1, const float* __restrict__ Wz2,
    const float* __restrict__ Wzout, const float* __restrict__ Wz0,
    const float* __restrict__ Wx1, const float* __restrict__ Wx2,
    const float* __restrict__ Wc0, const float* __restrict__ Wc1,
    const float* __restrict__ Wc2, const float* __restrict__ Cc,
    short* __restrict__ S1b, short* __restrict__ S1Tb,
    short* __restrict__ S2b, short* __restrict__ S2Tb,
    short* __restrict__ Wc0b, short* __restrict__ Wc1b, short* __restrict__ Wc2b,
    short* __restrict__ Ccb, short* __restrict__ W0Tb,
    short* __restrict__ Wx1Tb, short* __restrict__ Wx2Tb,
    float* __restrict__ so)
{
  const int idx = blockIdx.x * 256 + threadIdx.x;   // 0 .. NH*NH-1
  const int i = idx >> 10, p = idx & 1023;
  const float v1 = sp_f(Wz1[idx]);
  const short b1 = f2bf(v1);
  S1b[idx] = b1; S1Tb[p * NH + i] = b1;
  const float v2 = sp_f(Wz2[idx]);
  const short b2 = f2bf(v2);
  S2b[idx] = b2; S2Tb[p * NH + i] = b2;
  if (idx < NH) so[idx] = sp_f(Wzout[idx]);
  if (idx < NH * NC) {
    Wc0b[idx] = f2bf(Wc0[idx]);
    Wc1b[idx] = f2bf(Wc1[idx]);
    Wc2b[idx] = f2bf(Wc2[idx]);
  }
  if (idx < NB * NC) Ccb[idx] = f2bf(Cc[idx]);
  if (idx < NDIM * NH) {
    const int j = idx >> 10, pp = idx & 1023;   // out [32,1024]
    W0Tb[idx]  = f2bf(Wz0[pp * NDIM + j]);
    Wx1Tb[idx] = f2bf(Wx1[pp * NDIM + j]);
    Wx2Tb[idx] = f2bf(Wx2[pp * NDIM + j]);
  }
}

// ---------------- fp32 tiled GEMM, 3 X-terms in one dispatch; z=0 fuses layer-0 act ----------------
__global__ __launch_bounds__(256) void k_gemmx(
    const float* __restrict__ A,
    const float* __restrict__ B0, const float* __restrict__ B1,
    const float* __restrict__ B2,
    float* __restrict__ C0, float* __restrict__ C1, float* __restrict__ C2,
    int ldc,
    const float* __restrict__ bz0, const float* __restrict__ bc0,
    const float* __restrict__ anb0, const float* __restrict__ anl0,
    short* __restrict__ Z0b, float* __restrict__ G0, float* __restrict__ U0)
{
  const float* Bt = (blockIdx.z == 0) ? B0 : (blockIdx.z == 1) ? B1 : B2;
  float* C        = (blockIdx.z == 0) ? C0 : (blockIdx.z == 1) ? C1 : C2;
  __shared__ float As[16][68];
  __shared__ float Bs[16][68];
  const int tid  = threadIdx.y * 16 + threadIdx.x;
  const int arow = tid >> 2;
  const int acol = (tid & 3) << 2;
  const int m0 = blockIdx.y << 6;
  const int n0 = blockIdx.x << 6;

  float acc[4][4];
#pragma unroll
  for (int i = 0; i < 4; ++i)
#pragma unroll
    for (int j = 0; j < 4; ++j) acc[i][j] = 0.f;

  const int R = m0 + arow;
  for (int k0 = 0; k0 < NDIM; k0 += 16) {
    const float4 av = *reinterpret_cast<const float4*>(&A[(size_t)R * NDIM + k0 + acol]);
    As[acol + 0][arow] = av.x; As[acol + 1][arow] = av.y;
    As[acol + 2][arow] = av.z; As[acol + 3][arow] = av.w;
    const float4 bv = *reinterpret_cast<const float4*>(&Bt[(size_t)(n0 + arow) * NDIM + k0 + acol]);
    Bs[acol + 0][arow] = bv.x; Bs[acol + 1][arow] = bv.y;
    Bs[acol + 2][arow] = bv.z; Bs[acol + 3][arow] = bv.w;
    __syncthreads();
#pragma unroll
    for (int kk = 0; kk < 16; ++kk) {
      const float4 a  = *reinterpret_cast<const float4*>(&As[kk][threadIdx.y << 2]);
      const float4 bb = *reinterpret_cast<const float4*>(&Bs[kk][threadIdx.x << 2]);
      const float am[4] = {a.x, a.y, a.z, a.w};
      const float bn[4] = {bb.x, bb.y, bb.z, bb.w};
#pragma unroll
      for (int i2 = 0; i2 < 4; ++i2)
#pragma unroll
        for (int j2 = 0; j2 < 4; ++j2)
          acc[i2][j2] = fmaf(am[i2], bn[j2], acc[i2][j2]);
    }
    __syncthreads();
  }
#pragma unroll
  for (int i2 = 0; i2 < 4; ++i2) {
    const int row = m0 + (threadIdx.y << 2) + i2;
    const int col = n0 + (threadIdx.x << 2);
    float* cp = &C[(size_t)row * ldc + col];
    const float4 cur = *reinterpret_cast<const float4*>(cp);
    float o[4];
    o[0] = acc[i2][0] + cur.x; o[1] = acc[i2][1] + cur.y;
    o[2] = acc[i2][2] + cur.z; o[3] = acc[i2][3] + cur.w;
    if (blockIdx.z == 0) {
      short4v zb;
      float4 g4, u4;
      float gg[4], uu[4];
#pragma unroll
      for (int e = 0; e < 4; ++e) {
        const int cc = col + e;
        const float bias = bz0[cc] + bc0[cc] + anb0[cc];
        const float el = expf(anl0[cc]);
        const float a = (o[e] + bias) * el;
        const float pdf = expf(-0.5f * a * a);
        const float er = erff(a * SQRT_HALF);
        zb[e] = f2bf((SQRT_HPI * a * er + pdf + SQRT_HPI * a) * INV_SQRT2PI);
        gg[e] = 0.5f * (1.f + er) * el;
        uu[e] = pdf * INV_SQRT2PI * el * el;
      }
      const size_t oi = (size_t)row * NH + col;
      *(short4v*)&Z0b[oi] = zb;
      g4.x = gg[0]; g4.y = gg[1]; g4.z = gg[2]; g4.w = gg[3];
      u4.x = uu[0]; u4.y = uu[1]; u4.z = uu[2]; u4.w = uu[3];
      *(float4*)&G0[oi] = g4;
      *(float4*)&U0[oi] = u4;
    } else {
      float4 ov;
      ov.x = o[0]; ov.y = o[1]; ov.z = o[2]; ov.w = o[3];
      *reinterpret_cast<float4*>(cp) = ov;
    }
  }
}

// ---------------- bf16 MFMA GEMM, 128x128 tile, fp32 out (c-path), transposed tiles ----------------
__global__ __launch_bounds__(256) void k_m128(
    const short* __restrict__ A, const short* __restrict__ Bt,
    float* __restrict__ C, float scale, int K, int ldc)
{
  __shared__ short As[128 * 32];
  __shared__ short Bs[128 * 32];
  const int tid  = threadIdx.x;
  const int wave = tid >> 6, lane = tid & 63;
  const int m0 = blockIdx.x << 7, n0 = blockIdx.y << 7;   // XCD swizzle
  const int wm = (wave >> 1) << 6, wn = (wave & 1) << 6;
  const int qd = lane >> 4, md = lane & 15;
  const int sr = lane >> 2;
  const int sc = (lane & 3) << 3;

  float4v acc[4][4];
#pragma unroll
  for (int i = 0; i < 4; ++i)
#pragma unroll
    for (int j = 0; j < 4; ++j) acc[i][j] = (float4v)(0.f);

  for (int k0 = 0; k0 < K; k0 += 32) {
#pragma unroll
    for (int i = 0; i < 2; ++i) {
      const int ch  = wave * 2 + i;
      const int row = ch * 16 + sr;
      async_ld16(&A [(size_t)(m0 + row) * K + k0 + sc], &As[ch * 512]);
      async_ld16(&Bt[(size_t)(n0 + row) * K + k0 + sc], &Bs[ch * 512]);
    }
    __syncthreads();
    short8 af[4], bfr[4];
#pragma unroll
    for (int t = 0; t < 4; ++t) {
      af[t]  = *(const short8*)&As[(wm + t * 16 + md) * 32 + qd * 8];
      bfr[t] = *(const short8*)&Bs[(wn + t * 16 + md) * 32 + qd * 8];
    }
#pragma unroll
    for (int i = 0; i < 4; ++i)
#pragma unroll
      for (int j = 0; j < 4; ++j)
        acc[i][j] = __builtin_amdgcn_mfma_f32_16x16x32_bf16(bfr[j], af[i], acc[i][j], 0, 0, 0);
    __syncthreads();
  }

#pragma unroll
  for (int i = 0; i < 4; ++i) {
    const int rowg = m0 + wm + i * 16 + md;
#pragma unroll
    for (int j = 0; j < 4; ++j) {
      const int colb = n0 + wn + j * 16 + (qd << 2);
      float4 o;
      o.x = acc[i][j][0] * scale; o.y = acc[i][j][1] * scale;
      o.z = acc[i][j][2] * scale; o.w = acc[i][j][3] * scale;
      *reinterpret_cast<float4*>(&C[(size_t)rowg * ldc + colb]) = o;
    }
  }
}

// ---------------- bf16 MFMA GEMM, 128x64 tile (Jacobian GEMMs), A+B in LDS ----------------
// grid (CB*32/128, NH/64) — x = M-block (XCD locality on A). dvec PRE-SQRT'd.
// EPI 1: o1 = bf16((acc*scale + WxT) * dvec)                      [Q2]
// EPI 2: o1 = ..., o2 = bf16((acc*scale + WxT) * gvec)            [Q1, A2]
template<int EPI>
__global__ __launch_bounds__(256) void k_mgemm(
    const short* __restrict__ A, const short* __restrict__ Bt,
    short* __restrict__ o1, short* __restrict__ o2,
    const float* __restrict__ gvec, const float* __restrict__ dvec,
    const short* __restrict__ wepiT,
    float scale, int K, int b0)
{
  __shared__ short As[128 * 32];   // 8 KB
  __shared__ short Bs[64 * 32];    // 4 KB
  const int tid  = threadIdx.x;
  const int wave = tid >> 6, lane = tid & 63;
  const int m0 = blockIdx.x << 7, n0 = blockIdx.y << 6;   // 128 x 64 tile
  const int wm = (wave >> 1) << 6, wn = (wave & 1) << 5;  // wave: 64 x 32
  const int qd = lane >> 4, md = lane & 15;
  const int sr = lane >> 2;
  const int sc = (lane & 3) << 3;

  float4v acc[4][2];
#pragma unroll
  for (int i = 0; i < 4; ++i)
#pragma unroll
    for (int j = 0; j < 2; ++j) acc[i][j] = (float4v)(0.f);

  for (int k0 = 0; k0 < K; k0 += 32) {
    // 12 16-row chunks: 0..7 = A (128 rows), 8..11 = B (64 rows); 3 per wave
#pragma unroll
    for (int i = 0; i < 3; ++i) {
      const int ch = wave * 3 + i;
      if (ch < 8) {
        async_ld16(&A[(size_t)(m0 + ch * 16 + sr) * K + k0 + sc], &As[ch * 512]);
      } else {
        const int c2 = ch - 8;
        async_ld16(&Bt[(size_t)(n0 + c2 * 16 + sr) * K + k0 + sc], &Bs[c2 * 512]);
      }
    }
    __syncthreads();
    short8 af[4], bfr[2];
#pragma unroll
    for (int t = 0; t < 4; ++t)
      af[t]  = *(const short8*)&As[(wm + t * 16 + md) * 32 + qd * 8];
#pragma unroll
    for (int t = 0; t < 2; ++t)
      bfr[t] = *(const short8*)&Bs[(wn + t * 16 + md) * 32 + qd * 8];
#pragma unroll
    for (int i = 0; i < 4; ++i)
#pragma unroll
      for (int j = 0; j < 2; ++j)
        acc[i][j] = __builtin_amdgcn_mfma_f32_16x16x32_bf16(bfr[j], af[i], acc[i][j], 0, 0, 0);
    __syncthreads();
  }

  // transposed: lane holds orig row = m0+wm+i*16+md, cols = n0+wn+j*16+qd*4..+3
  const int bbase = b0 + ((m0 + wm) >> 5);
  const size_t bNH0 = (size_t)bbase * NH, bNH1 = bNH0 + NH;
  float4 dqA[2], dqB[2], ggA[2], ggB[2];
#pragma unroll
  for (int j = 0; j < 2; ++j) {
    const int colb = n0 + wn + j * 16 + (qd << 2);
    dqA[j] = *(const float4*)&dvec[bNH0 + colb];
    dqB[j] = *(const float4*)&dvec[bNH1 + colb];
    if constexpr (EPI == 2) {
      ggA[j] = *(const float4*)&gvec[bNH0 + colb];
      ggB[j] = *(const float4*)&gvec[bNH1 + colb];
    }
  }
#pragma unroll
  for (int i = 0; i < 4; ++i) {
    const int rowg = m0 + wm + i * 16 + md;
    const int j2 = rowg & 31;
#pragma unroll
    for (int j = 0; j < 2; ++j) {
      const int colb = n0 + wn + j * 16 + (qd << 2);
      const short4v wq = *(const short4v*)&wepiT[(size_t)j2 * NH + colb];
      const float4 dq = (i < 2) ? dqA[j] : dqB[j];
      const float dqv[4] = {dq.x, dq.y, dq.z, dq.w};
      float v[4];
      short4v o1v;
#pragma unroll
      for (int r = 0; r < 4; ++r) {
        v[r] = acc[i][j][r] * scale + bf2f(wq[r]);
        o1v[r] = f2bf(v[r] * dqv[r]);
      }
      *(short4v*)&o1[(size_t)rowg * NH + colb] = o1v;
      if constexpr (EPI == 2) {
        const float4 gg = (i < 2) ? ggA[j] : ggB[j];
        const float ggv[4] = {gg.x, gg.y, gg.z, gg.w};
        short4v o2v;
#pragma unroll
        for (int r = 0; r < 4; ++r) o2v[r] = f2bf(v[r] * ggv[r]);
        *(short4v*)&o2[(size_t)rowg * NH + colb] = o2v;
      }
    }
  }
}

// ---------------- bf16 MFMA GEMM, 64x64 tile, K-split partials (z=2, forward) ----------------
__global__ __launch_bounds__(256) void k_mgemm64s(
    const short* __restrict__ A, const short* __restrict__ Bt,
    float* __restrict__ Cpart)
{
  __shared__ short As[64 * 32];
  __shared__ short Bs[64 * 32];
  const int tid  = threadIdx.x;
  const int wave = tid >> 6, lane = tid & 63;
  const int m0 = blockIdx.x << 6, n0 = blockIdx.y << 6;   // XCD swizzle
  const int kb = blockIdx.z << 9;                          // 0 or 512
  const int wm = (wave >> 1) << 5, wn = (wave & 1) << 5;
  const int qd = lane >> 4, md = lane & 15;
  const int sr = lane >> 2;
  const int sc = (lane & 3) << 3;

  float4v acc[2][2];
#pragma unroll
  for (int i = 0; i < 2; ++i)
#pragma unroll
    for (int j = 0; j < 2; ++j) acc[i][j] = (float4v)(0.f);

  for (int k0 = kb; k0 < kb + 512; k0 += 32) {
    const int row = wave * 16 + sr;
    async_ld16(&A [(size_t)(m0 + row) * NH + k0 + sc], &As[wave * 512]);
    async_ld16(&Bt[(size_t)(n0 + row) * NH + k0 + sc], &Bs[wave * 512]);
    __syncthreads();
    short8 af[2], bfr[2];
#pragma unroll
    for (int t = 0; t < 2; ++t) {
      af[t]  = *(const short8*)&As[(wm + t * 16 + md) * 32 + qd * 8];
      bfr[t] = *(const short8*)&Bs[(wn + t * 16 + md) * 32 + qd * 8];
    }
#pragma unroll
    for (int i = 0; i < 2; ++i)
#pragma unroll
      for (int j = 0; j < 2; ++j)
        acc[i][j] = __builtin_amdgcn_mfma_f32_16x16x32_bf16(bfr[j], af[i], acc[i][j], 0, 0, 0);
    __syncthreads();
  }

  float* out = Cpart + (size_t)blockIdx.z * NB * NH;
#pragma unroll
  for (int i = 0; i < 2; ++i) {
    const int rowg = m0 + wm + i * 16 + md;
#pragma unroll
    for (int j = 0; j < 2; ++j) {
      const int colb = n0 + wn + j * 16 + (qd << 2);
      float4 o;
      o.x = acc[i][j][0]; o.y = acc[i][j][1];
      o.z = acc[i][j][2]; o.w = acc[i][j][3];
      *reinterpret_cast<float4*>(&out[(size_t)rowg * NH + colb]) = o;
    }
  }
}

// ---------------- bf16 MFMA GEMM, 64x64 tile, fused backward epilogues (unsplit) ----------------
// FEPI 3 (bw1): t=acc*scale; ob=bf16(t*auxA), of1=sqrt(max(t*auxB,0))   [E1b, SD1]
// FEPI 4 (bw0): t=acc*scale; ob=bf16(t*auxA), of1=t*auxB               [GT0b, D0]
template<int FEPI>
__global__ __launch_bounds__(256) void k_mgemm64f(
    const short* __restrict__ A, const short* __restrict__ Bt,
    const float* __restrict__ auxA, const float* __restrict__ auxB,
    short* __restrict__ ob, float* __restrict__ of1,
    float scale)
{
  __shared__ short As[64 * 32];
  __shared__ short Bs[64 * 32];
  const int tid  = threadIdx.x;
  const int wave = tid >> 6, lane = tid & 63;
  const int m0 = blockIdx.x << 6, n0 = blockIdx.y << 6;
  const int wm = (wave >> 1) << 5, wn = (wave & 1) << 5;
  const int qd = lane >> 4, md = lane & 15;
  const int sr = lane >> 2;
  const int sc = (lane & 3) << 3;

  float4v acc[2][2];
#pragma unroll
  for (int i = 0; i < 2; ++i)
#pragma unroll
    for (int j = 0; j < 2; ++j) acc[i][j] = (float4v)(0.f);

  for (int k0 = 0; k0 < NH; k0 += 32) {
    const int row = wave * 16 + sr;
    async_ld16(&A [(size_t)(m0 + row) * NH + k0 + sc], &As[wave * 512]);
    async_ld16(&Bt[(size_t)(n0 + row) * NH + k0 + sc], &Bs[wave * 512]);
    __syncthreads();
    short8 af[2], bfr[2];
#pragma unroll
    for (int t = 0; t < 2; ++t) {
      af[t]  = *(const short8*)&As[(wm + t * 16 + md) * 32 + qd * 8];
      bfr[t] = *(const short8*)&Bs[(wn + t * 16 + md) * 32 + qd * 8];
    }
#pragma unroll
    for (int i = 0; i < 2; ++i)
#pragma unroll
      for (int j = 0; j < 2; ++j)
        acc[i][j] = __builtin_amdgcn_mfma_f32_16x16x32_bf16(bfr[j], af[i], acc[i][j], 0, 0, 0);
    __syncthreads();
  }

#pragma unroll
  for (int i = 0; i < 2; ++i) {
    const int rowg = m0 + wm + i * 16 + md;
#pragma unroll
    for (int j = 0; j < 2; ++j) {
      const int colb = n0 + wn + j * 16 + (qd << 2);
      const size_t oi = (size_t)rowg * NH + colb;
      const float4 g4 = *(const float4*)&auxA[oi];
      const float4 u4 = *(const float4*)&auxB[oi];
      const float gv[4] = {g4.x, g4.y, g4.z, g4.w};
      const float uv[4] = {u4.x, u4.y, u4.z, u4.w};
      short4v eb;
      float sd[4];
#pragma unroll
      for (int r = 0; r < 4; ++r) {
        const float t = acc[i][j][r] * scale;
        eb[r] = f2bf(t * gv[r]);
        if constexpr (FEPI == 3) sd[r] = sqrtf(fmaxf(t * uv[r], 0.f));
        else                     sd[r] = t * uv[r];
      }
      *(short4v*)&ob[oi] = eb;
      float4 s4; s4.x = sd[0]; s4.y = sd[1]; s4.z = sd[2]; s4.w = sd[3];
      *(float4*)&of1[oi] = s4;
    }
  }
}

// ---------------- activation (layer 1): sum HP halves, writes Zbf, G, U ----------------
__global__ __launch_bounds__(256) void k_act(
    const float* __restrict__ HP2, const float* __restrict__ HPC_l,
    const float* __restrict__ bA, const float* __restrict__ bB,
    const float* __restrict__ bC,
    const float* __restrict__ anb, const float* __restrict__ anl,
    short* __restrict__ Zbf, float* __restrict__ G, float* __restrict__ U,
    float scale)
{
  const int idx = blockIdx.x * 256 + threadIdx.x;
  const int i = idx & 1023;
  const float bias = bA[i] + bB[i] + bC[i] + anb[i];
  const float el = expf(anl[i]);
  const float hc = HPC_l[(size_t)(idx >> 10) * (3 * NH) + i];
  const float hp = (HP2[idx] + HP2[(size_t)NB * NH + idx]) * scale;
  const float a = (hp + hc + bias) * el;
  const float pdf = expf(-0.5f * a * a);
  const float er = erff(a * SQRT_HALF);
  Zbf[idx] = f2bf((SQRT_HPI * a * er + pdf + SQRT_HPI * a) * INV_SQRT2PI);
  G[idx] = 0.5f * (1.f + er) * el;
  U[idx] = pdf * INV_SQRT2PI * el * el;
}

// ---------------- activation (layer 2): SD2 = sqrt(t2*u2), D2g bf16 ----------------
__global__ __launch_bounds__(256) void k_act2(
    const float* __restrict__ HP2, const float* __restrict__ HPC_l,
    const float* __restrict__ bA, const float* __restrict__ bB,
    const float* __restrict__ bC,
    const float* __restrict__ anb, const float* __restrict__ anl,
    const float* __restrict__ so,
    float* __restrict__ SD2, short* __restrict__ D2gbf, float scale)
{
  const int idx = blockIdx.x * 256 + threadIdx.x;
  const int i = idx & 1023;
  const float bias = bA[i] + bB[i] + bC[i] + anb[i];
  const float el = expf(anl[i]);
  const float hc = HPC_l[(size_t)(idx >> 10) * (3 * NH) + i];
  const float hp = (HP2[idx] + HP2[(size_t)NB * NH + idx]) * scale;
  const float a = (hp + hc + bias) * el;
  const float pdf = expf(-0.5f * a * a);
  const float er = erff(a * SQRT_HALF);
  const float g = 0.5f * (1.f + er) * el;
  const float u = pdf * INV_SQRT2PI * el * el;
  const float t2 = so[i] * (1.f / NH);
  SD2[idx] = sqrtf(fmaxf(t2 * u, 0.f));
  D2gbf[idx] = f2bf(t2 * g);
}

// ---------------- Ah1[r,p] = bf16(G0[b,p] * W0T[j,p]) (coalesced) ----------------
__global__ __launch_bounds__(256) void k_scale0(
    const float* __restrict__ G0, const short* __restrict__ W0Tb,
    short* __restrict__ Ah1, int b0)
{
  const int idx = blockIdx.x * 256 + threadIdx.x;
  const int p = idx & 1023, r = idx >> 10;
  const int b = b0 + (r >> 5), j = r & 31;
  Ah1[idx] = f2bf(G0[(size_t)b * NH + p] * bf2f(W0Tb[(size_t)j * NH + p]));
}

// ---------------- f-GEMM: MFMA partials of [NB,NH]@[NH,32] per term/k-split ----------------
__global__ __launch_bounds__(256) void k_fgemm(
    const short* __restrict__ A0, const short* __restrict__ A1,
    const short* __restrict__ A2,
    const short* __restrict__ W0T, const short* __restrict__ W1T,
    const short* __restrict__ W2T,
    float* __restrict__ partF)
{
  const int mb = blockIdx.x;
  const int ks = blockIdx.y;
  const int term = blockIdx.z;
  const short* A  = (term == 0) ? A0 : (term == 1) ? A1 : A2;
  const short* WT = (term == 0) ? W0T : (term == 1) ? W1T : W2T;
  const int wave = threadIdx.x >> 6, lane = threadIdx.x & 63;
  const int qd = lane >> 4, md = lane & 15;
  const int m0 = mb * 128 + wave * 32;
  const int kbeg = ks * (NH / KSF);

  float4v acc[2][2];
#pragma unroll
  for (int i = 0; i < 2; ++i)
#pragma unroll
    for (int j = 0; j < 2; ++j) acc[i][j] = (float4v)(0.f);

  for (int k0 = kbeg; k0 < kbeg + NH / KSF; k0 += 32) {
    const int kk = k0 + qd * 8;
    short8 af[2], bfr[2];
    af[0]  = *(const short8*)&A[(size_t)(m0 + md) * NH + kk];
    af[1]  = *(const short8*)&A[(size_t)(m0 + 16 + md) * NH + kk];
    bfr[0] = *(const short8*)&WT[(size_t)md * NH + kk];
    bfr[1] = *(const short8*)&WT[(size_t)(16 + md) * NH + kk];
#pragma unroll
    for (int i = 0; i < 2; ++i)
#pragma unroll
      for (int j = 0; j < 2; ++j)
        acc[i][j] = __builtin_amdgcn_mfma_f32_16x16x32_bf16(af[i], bfr[j], acc[i][j], 0, 0, 0);
  }

  float* out = &partF[(size_t)(term * KSF + ks) * NB * 32];
#pragma unroll
  for (int i = 0; i < 2; ++i)
#pragma unroll
    for (int j = 0; j < 2; ++j)
#pragma unroll
      for (int r = 0; r < 4; ++r) {
        const int row = m0 + i * 16 + qd * 4 + r;
        const int col = j * 16 + md;
        out[(size_t)row * 32 + col] = acc[i][j][r];
      }
}

// ---------------- reduce f partials + epilogue ----------------
__global__ __launch_bounds__(256) void k_fred(
    const float* __restrict__ partF, const float* __restrict__ X,
    const float* __restrict__ Wxout,
    const float* __restrict__ w0p, const float* __restrict__ w1p,
    float* __restrict__ outF)
{
  const int e = blockIdx.x * 256 + threadIdx.x;
  float s = 0.f;
#pragma unroll
  for (int p = 0; p < 3 * KSF; ++p) s += partF[(size_t)p * NB * 32 + e];
  const float spw0 = sp_f(w0p[0]);
  const float spw1 = sp_f(w1p[0]);
  outF[e] = spw1 * (s + Wxout[e & 31]) + spw0 * X[e];
}

// ---------------- K-split per-sample Gram partials ----------------
__global__ __launch_bounds__(256) void k_gram(
    const short* __restrict__ Q1, const short* __restrict__ Q2,
    const short* __restrict__ W0T, const float* __restrict__ D0,
    float* __restrict__ partH, int b0)
{
  const int ns = blockIdx.x, bl = blockIdx.y;
  const int b = b0 + bl;
  const int wave = threadIdx.x >> 6, lane = threadIdx.x & 63;
  const int wm = (wave >> 1) << 4, wn = (wave & 1) << 4;
  const int qd = lane >> 4, md = lane & 15;
  const int kbeg = ns << 7;
  const size_t rb = (size_t)bl * 32 * NH;

  float4v acc = (float4v)(0.f);

  for (int k0 = kbeg; k0 < kbeg + 128; k0 += 32) {
    const int kk = k0 + qd * 8;
    const short8 ar = *(const short8*)&W0T[(size_t)(wm + md) * NH + kk];
    float dd[8];
    *(float4*)&dd[0] = *(const float4*)&D0[(size_t)b * NH + kk];
    *(float4*)&dd[4] = *(const float4*)&D0[(size_t)b * NH + kk + 4];
    short8 af;
#pragma unroll
    for (int e = 0; e < 8; ++e) af[e] = f2bf(bf2f(ar[e]) * dd[e]);
    const short8 bfr = *(const short8*)&W0T[(size_t)(wn + md) * NH + kk];
    acc = __builtin_amdgcn_mfma_f32_16x16x32_bf16(af, bfr, acc, 0, 0, 0);
  }
#pragma unroll
  for (int l = 0; l < 2; ++l) {
    const short* Q = (l == 0) ? Q1 : Q2;
    for (int k0 = kbeg; k0 < kbeg + 128; k0 += 32) {
      const int kk = k0 + qd * 8;
      const short8 af  = *(const short8*)&Q[rb + (size_t)(wm + md) * NH + kk];
      const short8 bfr = *(const short8*)&Q[rb + (size_t)(wn + md) * NH + kk];
      acc = __builtin_amdgcn_mfma_f32_16x16x32_bf16(af, bfr, acc, 0, 0, 0);
    }
  }

  float* out = &partH[((size_t)bl * NS + ns) * 1024];
#pragma unroll
  for (int r = 0; r < 4; ++r)
    out[(wm + qd * 4 + r) * 32 + (wn + md)] = acc[r];
}

// ---------------- reduce partials + Cholesky logdet ----------------
__global__ __launch_bounds__(256) void k_gram2(
    const float* __restrict__ partH,
    const float* __restrict__ w0p, const float* __restrict__ w1p,
    float* __restrict__ outLD, int b0)
{
  const int bl = blockIdx.x, b = b0 + bl, tid = threadIdx.x;
  __shared__ float sH[32][33];
  __shared__ float sred[32];
  const float spw0 = sp_f(w0p[0]);
  const float spw1 = sp_f(w1p[0]);
  const float* base = &partH[(size_t)bl * NS * 1024];
#pragma unroll
  for (int r = 0; r < 4; ++r) {
    const int e = r * 256 + tid;
    float s = 0.f;
#pragma unroll
    for (int ns = 0; ns < NS; ++ns) s += base[ns * 1024 + e];
    float h = s * spw1;
    const int row = e >> 5, col = e & 31;
    if (row == col) h += spw0;
    sH[row][col] = h;
  }
  __syncthreads();

  float ldacc = 0.f;
  for (int c = 0; c < 32; ++c) {
    if (tid >= c && tid < 32) {
      float s = sH[tid][c];
      for (int m = 0; m < c; ++m) s -= sH[tid][m] * sH[c][m];
      sred[tid] = s;
    }
    __syncthreads();
    const float sc = sred[c];
    if (tid >= c && tid < 32) {
      const float lcc = sqrtf(sc);
      sH[tid][c] = (tid == c) ? lcc : sred[tid] / lcc;
    }
    ldacc += logf(sc);
    __syncthreads();
  }
  if (tid == 0) outLD[b] = ldacc;
}

// ---------------- launcher ----------------
extern "C" void kernel_launch(void* const* d_in, const int* in_sizes, int n_in,
                              void* d_out, int out_size, void* d_ws, size_t ws_size,
                              hipStream_t stream)
{
  const float* X    = (const float*)d_in[0];
  const float* Cc   = (const float*)d_in[1];
  const float* w0   = (const float*)d_in[2];
  const float* w1   = (const float*)d_in[3];
  const float* Wz0w = (const float*)d_in[4];
  const float* Wz0b = (const float*)d_in[5];
  const float* Wc0w = (const float*)d_in[6];
  const float* Wc0b = (const float*)d_in[7];
  const float* an0b = (const float*)d_in[8];
  const float* an0l = (const float*)d_in[9];
  const float* Wz1w = (const float*)d_in[10];
  const float* Wz1b = (const float*)d_in[11];
  const float* Wx1w = (const float*)d_in[12];
  const float* Wx1b = (const float*)d_in[13];
  const float* Wc1w = (const float*)d_in[14];
  const float* Wc1b = (const float*)d_in[15];
  const float* an1b = (const float*)d_in[16];
  const float* an1l = (const float*)d_in[17];
  const float* Wz2w = (const float*)d_in[18];
  const float* Wz2b = (const float*)d_in[19];
  const float* Wx2w = (const float*)d_in[20];
  const float* Wx2b = (const float*)d_in[21];
  const float* Wc2w = (const float*)d_in[22];
  const float* Wc2b = (const float*)d_in[23];
  const float* an2b = (const float*)d_in[24];
  const float* an2l = (const float*)d_in[25];
  const float* Wzoutw = (const float*)d_in[26];
  const float* Wxoutw = (const float*)d_in[27];
  // d_in[28] (Wcout_w): constant in x -> no grad/Hessian contribution.

  float* ws = (float*)d_ws;
  size_t off = 0;
  auto alloc = [&](size_t n) {
    float* p = ws + off; off += (n + 3) & ~(size_t)3; return p;
  };
  const size_t HH = (size_t)NH * NH;
  const size_t BH = (size_t)NB * NH;

  short* S1b  = (short*)alloc(HH / 2);
  short* S2b  = (short*)alloc(HH / 2);
  short* S1Tb = (short*)alloc(HH / 2);
  short* S2Tb = (short*)alloc(HH / 2);
  short* Wc0bb = (short*)alloc((size_t)NH * NC / 2);
  short* Wc1bb = (short*)alloc((size_t)NH * NC / 2);
  short* Wc2bb = (short*)alloc((size_t)NH * NC / 2);
  short* Ccb  = (short*)alloc((size_t)NB * NC / 2);
  short* W0Tb = (short*)alloc((size_t)NDIM * NH / 2);
  short* Wx1Tb = (short*)alloc((size_t)NDIM * NH / 2);
  short* Wx2Tb = (short*)alloc((size_t)NDIM * NH / 2);
  float* so   = alloc(NH);
  float* HP2  = alloc(2 * BH);                // K-split GEMM partials
  float* HPC  = alloc((size_t)NB * 3 * NH);   // c-path + X-terms [NB, 3*NH]
  short* Z0b  = (short*)alloc(BH / 2);
  short* Z1b  = (short*)alloc(BH / 2);
  float* G0   = alloc(BH);
  float* U0   = alloc(BH);
  float* G1   = alloc(BH);
  float* U1   = alloc(BH);
  float* SD2  = alloc(BH);
  short* D2gb = (short*)alloc(BH / 2);
  short* E1b  = (short*)alloc(BH / 2);
  float* SD1  = alloc(BH);
  float* D0   = alloc(BH);
  short* GT0b = (short*)alloc(BH / 2);
  float* partF = alloc((size_t)3 * KSF * NB * 32);

  // chunk buffers: Ah1, A2, Q1 (bf16); Q2 aliases Ah1 (dead after GEMM1)
  const size_t avail_f = ws_size / sizeof(float);
  int CB = 32;
  const int cands[6] = {1024, 512, 256, 128, 64, 32};
  for (int ci = 0; ci < 6; ++ci) {
    const size_t need = off + 3 * ((size_t)cands[ci] * 32 * NH / 2 + 4)
                      + (size_t)cands[ci] * NS * 1024 + 64;
    if (need <= avail_f) { CB = cands[ci]; break; }
  }
  const size_t chunk_sh = (size_t)CB * 32 * NH;
  short* Ah1 = (short*)alloc(chunk_sh / 2);
  short* A2b = (short*)alloc(chunk_sh / 2);
  short* Q1b = (short*)alloc(chunk_sh / 2);
  short* Q2b = Ah1;
  float* partH = alloc((size_t)CB * NS * 1024);

  float* outF  = (float*)d_out;
  float* outLD = (float*)d_out + NB * NDIM;

  const dim3 blk2(16, 16);
  const dim3 gridXz(16, NB / 64, 3);        // fused X-terms (+ act0 in z=0)
  const dim3 gridE(NB * NH / 256);
  const dim3 grid64s(NB / 64, NH / 64, 2);  // K-split 64-tile mfma (512 blocks)
  const dim3 grid64u(NB / 64, NH / 64);     // unsplit fused-backward 64-tile
  const dim3 gridC(NB / 128, 3 * NH / 128); // fused c-GEMM
  const float invH = 1.0f / (float)NH;

  k_prep<<<dim3(HH / 256), dim3(256), 0, stream>>>(
      Wz1w, Wz2w, Wzoutw, Wz0w, Wx1w, Wx2w, Wc0w, Wc1w, Wc2w, Cc,
      S1b, S1Tb, S2b, S2Tb, Wc0bb, Wc1bb, Wc2bb, Ccb, W0Tb, Wx1Tb, Wx2Tb, so);

  // HPC = c-path (bf16 MFMA), then X-terms (fp32) with fused layer-0 activation (z=0)
  k_m128<<<gridC, dim3(256), 0, stream>>>(Ccb, Wc0bb, HPC, 1.f, NC, 3 * NH);
  k_gemmx<<<gridXz, blk2, 0, stream>>>(X, Wz0w, Wx1w, Wx2w,
                                       HPC + 0 * NH, HPC + 1 * NH, HPC + 2 * NH, 3 * NH,
                                       Wz0b, Wc0b, an0b, an0l, Z0b, G0, U0);

  // layer 1
  k_mgemm64s<<<grid64s, dim3(256), 0, stream>>>(Z0b, S1b, HP2);
  k_act<<<gridE, dim3(256), 0, stream>>>(HP2, HPC + 1 * NH, Wz1b, Wx1b, Wc1b,
                                         an1b, an1l, Z1b, G1, U1, invH);
  // layer 2
  k_mgemm64s<<<grid64s, dim3(256), 0, stream>>>(Z1b, S2b, HP2);
  k_act2<<<gridE, dim3(256), 0, stream>>>(HP2, HPC + 2 * NH, Wz2b, Wx2b, Wc2b,
                                          an2b, an2l, so, SD2, D2gb, invH);
  // backward sensitivities (fused epilogues, unsplit)
  k_mgemm64f<3><<<grid64u, dim3(256), 0, stream>>>(D2gb, S2Tb, G1, U1, E1b, SD1, invH);
  k_mgemm64f<4><<<grid64u, dim3(256), 0, stream>>>(E1b, S1Tb, G0, U0, GT0b, D0, invH);

  // f (grad) via MFMA partials + reduce
  k_fgemm<<<dim3(8, KSF, 3), dim3(256), 0, stream>>>(
      GT0b, E1b, D2gb, W0Tb, Wx1Tb, Wx2Tb, partF);
  k_fred<<<dim3(NB * 32 / 256), dim3(256), 0, stream>>>(
      partF, X, Wxoutw, w0, w1, outF);

  // Jacobian propagation + K-split Gram + Cholesky, chunked over samples
  const dim3 gridJ(CB * 32 / 128, NH / 64);    // 128x64 tile (x = M-block, XCD swizzle)
  const dim3 gridS((size_t)CB * 32 * NH / 256);
  const dim3 gridG(NS, CB);
  for (int b0 = 0; b0 < NB; b0 += CB) {
    k_scale0<<<gridS, dim3(256), 0, stream>>>(G0, W0Tb, Ah1, b0);
    k_mgemm<2><<<gridJ, dim3(256), 0, stream>>>(Ah1, S1b, Q1b, A2b,
                                                G1, SD1, Wx1Tb, invH, NH, b0);
    k_mgemm<1><<<gridJ, dim3(256), 0, stream>>>(A2b, S2b, Q2b, nullptr,
                                                nullptr, SD2, Wx2Tb, invH, NH, b0);
    k_gram<<<gridG, dim3(256), 0, stream>>>(Q1b, Q2b, W0Tb, D0, partH, b0);
    k_gram2<<<dim3(CB), dim3(256), 0, stream>>>(partH, w0, w1, outLD, b0);
  }
}

// Round 13
// 648.176 us; speedup vs baseline: 1.2218x; 1.0486x over previous
//
#include <hip/hip_runtime.h>

constexpr int NB   = 1024;  // batch
constexpr int NDIM = 32;    // x dim
constexpr int NH   = 1024;  // hidden dim
constexpr int NC   = 512;   // context dim
constexpr int NS   = 8;     // K-splits in k_gram
constexpr int KSF  = 8;     // K-splits per term in k_fgemm

constexpr float INV_SQRT2PI = 0.3989422804014327f;
constexpr float SQRT_HALF   = 0.70710678118654752f;
constexpr float SQRT_HPI    = 1.2533141373155003f;

typedef __attribute__((ext_vector_type(8))) short short8;
typedef __attribute__((ext_vector_type(4))) short short4v;
typedef __attribute__((ext_vector_type(4))) float float4v;

__device__ __forceinline__ float sp_f(float x) {
  return (x > 20.f) ? x : log1pf(expf(x));
}

__device__ __forceinline__ short f2bf(float f) {
  union { float f; unsigned u; } x; x.f = f;
  const unsigned r = x.u + 0x7fffu + ((x.u >> 16) & 1u);
  return (short)(r >> 16);
}

__device__ __forceinline__ float bf2f(short s) {
  union { unsigned u; float f; } c;
  c.u = ((unsigned)(unsigned short)s) << 16;
  return c.f;
}

__device__ __forceinline__ void async_ld16(const void* g, void* l) {
  __builtin_amdgcn_global_load_lds(
      (const __attribute__((address_space(1))) void*)g,
      (__attribute__((address_space(3))) void*)l, 16, 0, 0);
}

// ---------------- prep ----------------
__global__ __launch_bounds__(256) void k_prep(
    const float* __restrict__ Wz1, const float* __restrict__ Wz2,
    const float* __restrict__ Wzout, const float* __restrict__ Wz0,
    const float* __restrict__ Wx1, const float* __restrict__ Wx2,
    const float* __restrict__ Wc0, const float* __restrict__ Wc1,
    const float* __restrict__ Wc2, const float* __restrict__ Cc,
    short* __restrict__ S1b, short* __restrict__ S1Tb,
    short* __restrict__ S2b, short* __restrict__ S2Tb,
    short* __restrict__ Wc0b, short* __restrict__ Wc1b, short* __restrict__ Wc2b,
    short* __restrict__ Ccb, short* __restrict__ W0Tb,
    short* __restrict__ Wx1Tb, short* __restrict__ Wx2Tb,
    float* __restrict__ so)
{
  const int idx = blockIdx.x * 256 + threadIdx.x;   // 0 .. NH*NH-1
  const int i = idx >> 10, p = idx & 1023;
  const float v1 = sp_f(Wz1[idx]);
  const short b1 = f2bf(v1);
  S1b[idx] = b1; S1Tb[p * NH + i] = b1;
  const float v2 = sp_f(Wz2[idx]);
  const short b2 = f2bf(v2);
  S2b[idx] = b2; S2Tb[p * NH + i] = b2;
  if (idx < NH) so[idx] = sp_f(Wzout[idx]);
  if (idx < NH * NC) {
    Wc0b[idx] = f2bf(Wc0[idx]);
    Wc1b[idx] = f2bf(Wc1[idx]);
    Wc2b[idx] = f2bf(Wc2[idx]);
  }
  if (idx < NB * NC) Ccb[idx] = f2bf(Cc[idx]);
  if (idx < NDIM * NH) {
    const int j = idx >> 10, pp = idx & 1023;   // out [32,1024]
    W0Tb[idx]  = f2bf(Wz0[pp * NDIM + j]);
    Wx1Tb[idx] = f2bf(Wx1[pp * NDIM + j]);
    Wx2Tb[idx] = f2bf(Wx2[pp * NDIM + j]);
  }
}

// ---------------- fp32 tiled GEMM, 3 X-terms in one dispatch; z=0 fuses layer-0 act ----------------
__global__ __launch_bounds__(256) void k_gemmx(
    const float* __restrict__ A,
    const float* __restrict__ B0, const float* __restrict__ B1,
    const float* __restrict__ B2,
    float* __restrict__ C0, float* __restrict__ C1, float* __restrict__ C2,
    int ldc,
    const float* __restrict__ bz0, const float* __restrict__ bc0,
    const float* __restrict__ anb0, const float* __restrict__ anl0,
    short* __restrict__ Z0b, float* __restrict__ G0, float* __restrict__ U0)
{
  const float* Bt = (blockIdx.z == 0) ? B0 : (blockIdx.z == 1) ? B1 : B2;
  float* C        = (blockIdx.z == 0) ? C0 : (blockIdx.z == 1) ? C1 : C2;
  __shared__ float As[16][68];
  __shared__ float Bs[16][68];
  const int tid  = threadIdx.y * 16 + threadIdx.x;
  const int arow = tid >> 2;
  const int acol = (tid & 3) << 2;
  const int m0 = blockIdx.y << 6;
  const int n0 = blockIdx.x << 6;

  float acc[4][4];
#pragma unroll
  for (int i = 0; i < 4; ++i)
#pragma unroll
    for (int j = 0; j < 4; ++j) acc[i][j] = 0.f;

  const int R = m0 + arow;
  for (int k0 = 0; k0 < NDIM; k0 += 16) {
    const float4 av = *reinterpret_cast<const float4*>(&A[(size_t)R * NDIM + k0 + acol]);
    As[acol + 0][arow] = av.x; As[acol + 1][arow] = av.y;
    As[acol + 2][arow] = av.z; As[acol + 3][arow] = av.w;
    const float4 bv = *reinterpret_cast<const float4*>(&Bt[(size_t)(n0 + arow) * NDIM + k0 + acol]);
    Bs[acol + 0][arow] = bv.x; Bs[acol + 1][arow] = bv.y;
    Bs[acol + 2][arow] = bv.z; Bs[acol + 3][arow] = bv.w;
    __syncthreads();
#pragma unroll
    for (int kk = 0; kk < 16; ++kk) {
      const float4 a  = *reinterpret_cast<const float4*>(&As[kk][threadIdx.y << 2]);
      const float4 bb = *reinterpret_cast<const float4*>(&Bs[kk][threadIdx.x << 2]);
      const float am[4] = {a.x, a.y, a.z, a.w};
      const float bn[4] = {bb.x, bb.y, bb.z, bb.w};
#pragma unroll
      for (int i2 = 0; i2 < 4; ++i2)
#pragma unroll
        for (int j2 = 0; j2 < 4; ++j2)
          acc[i2][j2] = fmaf(am[i2], bn[j2], acc[i2][j2]);
    }
    __syncthreads();
  }
#pragma unroll
  for (int i2 = 0; i2 < 4; ++i2) {
    const int row = m0 + (threadIdx.y << 2) + i2;
    const int col = n0 + (threadIdx.x << 2);
    float* cp = &C[(size_t)row * ldc + col];
    const float4 cur = *reinterpret_cast<const float4*>(cp);
    float o[4];
    o[0] = acc[i2][0] + cur.x; o[1] = acc[i2][1] + cur.y;
    o[2] = acc[i2][2] + cur.z; o[3] = acc[i2][3] + cur.w;
    if (blockIdx.z == 0) {
      short4v zb;
      float4 g4, u4;
      float gg[4], uu[4];
#pragma unroll
      for (int e = 0; e < 4; ++e) {
        const int cc = col + e;
        const float bias = bz0[cc] + bc0[cc] + anb0[cc];
        const float el = expf(anl0[cc]);
        const float a = (o[e] + bias) * el;
        const float pdf = expf(-0.5f * a * a);
        const float er = erff(a * SQRT_HALF);
        zb[e] = f2bf((SQRT_HPI * a * er + pdf + SQRT_HPI * a) * INV_SQRT2PI);
        gg[e] = 0.5f * (1.f + er) * el;
        uu[e] = pdf * INV_SQRT2PI * el * el;
      }
      const size_t oi = (size_t)row * NH + col;
      *(short4v*)&Z0b[oi] = zb;
      g4.x = gg[0]; g4.y = gg[1]; g4.z = gg[2]; g4.w = gg[3];
      u4.x = uu[0]; u4.y = uu[1]; u4.z = uu[2]; u4.w = uu[3];
      *(float4*)&G0[oi] = g4;
      *(float4*)&U0[oi] = u4;
    } else {
      float4 ov;
      ov.x = o[0]; ov.y = o[1]; ov.z = o[2]; ov.w = o[3];
      *reinterpret_cast<float4*>(cp) = ov;
    }
  }
}

// ---------------- bf16 MFMA GEMM, 128x128 tile, fp32 out (c-path), transposed tiles ----------------
__global__ __launch_bounds__(256) void k_m128(
    const short* __restrict__ A, const short* __restrict__ Bt,
    float* __restrict__ C, float scale, int K, int ldc)
{
  __shared__ short As[128 * 32];
  __shared__ short Bs[128 * 32];
  const int tid  = threadIdx.x;
  const int wave = tid >> 6, lane = tid & 63;
  const int m0 = blockIdx.x << 7, n0 = blockIdx.y << 7;   // XCD swizzle
  const int wm = (wave >> 1) << 6, wn = (wave & 1) << 6;
  const int qd = lane >> 4, md = lane & 15;
  const int sr = lane >> 2;
  const int sc = (lane & 3) << 3;

  float4v acc[4][4];
#pragma unroll
  for (int i = 0; i < 4; ++i)
#pragma unroll
    for (int j = 0; j < 4; ++j) acc[i][j] = (float4v)(0.f);

  for (int k0 = 0; k0 < K; k0 += 32) {
#pragma unroll
    for (int i = 0; i < 2; ++i) {
      const int ch  = wave * 2 + i;
      const int row = ch * 16 + sr;
      async_ld16(&A [(size_t)(m0 + row) * K + k0 + sc], &As[ch * 512]);
      async_ld16(&Bt[(size_t)(n0 + row) * K + k0 + sc], &Bs[ch * 512]);
    }
    __syncthreads();
    short8 af[4], bfr[4];
#pragma unroll
    for (int t = 0; t < 4; ++t) {
      af[t]  = *(const short8*)&As[(wm + t * 16 + md) * 32 + qd * 8];
      bfr[t] = *(const short8*)&Bs[(wn + t * 16 + md) * 32 + qd * 8];
    }
#pragma unroll
    for (int i = 0; i < 4; ++i)
#pragma unroll
      for (int j = 0; j < 4; ++j)
        acc[i][j] = __builtin_amdgcn_mfma_f32_16x16x32_bf16(bfr[j], af[i], acc[i][j], 0, 0, 0);
    __syncthreads();
  }

#pragma unroll
  for (int i = 0; i < 4; ++i) {
    const int rowg = m0 + wm + i * 16 + md;
#pragma unroll
    for (int j = 0; j < 4; ++j) {
      const int colb = n0 + wn + j * 16 + (qd << 2);
      float4 o;
      o.x = acc[i][j][0] * scale; o.y = acc[i][j][1] * scale;
      o.z = acc[i][j][2] * scale; o.w = acc[i][j][3] * scale;
      *reinterpret_cast<float4*>(&C[(size_t)rowg * ldc + colb]) = o;
    }
  }
}

// ---------------- bf16 MFMA GEMM, 128x64 tile, BK=64 + XOR-swizzled LDS (Jacobian GEMMs) ----------------
// Swizzle: chunk c (16B) of row r stored at slot c ^ (r&7). Staging permutes SOURCE
// addresses (lane-contiguous LDS dests preserved for global_load_lds); reads invert it.
// grid (CB*32/128, NH/64) — x = M-block (XCD locality on A). dvec PRE-SQRT'd.
// EPI 1: o1 = bf16((acc*scale + WxT) * dvec)                      [Q2]
// EPI 2: o1 = ..., o2 = bf16((acc*scale + WxT) * gvec)            [Q1, A2]
template<int EPI>
__global__ __launch_bounds__(256) void k_mgemm(
    const short* __restrict__ A, const short* __restrict__ Bt,
    short* __restrict__ o1, short* __restrict__ o2,
    const float* __restrict__ gvec, const float* __restrict__ dvec,
    const short* __restrict__ wepiT,
    float scale, int K, int b0)
{
  __shared__ short As[128 * 64];   // 16 KB
  __shared__ short Bs[64 * 64];    // 8 KB
  const int tid  = threadIdx.x;
  const int wave = tid >> 6, lane = tid & 63;
  const int m0 = blockIdx.x << 7, n0 = blockIdx.y << 6;   // 128 x 64 tile
  const int wm = (wave >> 1) << 6, wn = (wave & 1) << 5;  // wave: 64 x 32
  const int qd = lane >> 4, md = lane & 15;
  const int lr8 = lane >> 3;        // row-within-8 for staging
  const int lg  = (lane & 7) ^ lr8; // swizzled source chunk (slot = lane&7)
  const int mS  = md & 7;           // read-side swizzle key

  float4v acc[4][2];
#pragma unroll
  for (int i = 0; i < 4; ++i)
#pragma unroll
    for (int j = 0; j < 2; ++j) acc[i][j] = (float4v)(0.f);

  for (int k0 = 0; k0 < K; k0 += 64) {
    // A: 4 issues/wave, each = 8 rows x 8 chunks (64 chunks, one per lane)
#pragma unroll
    for (int i = 0; i < 4; ++i) {
      const int g8  = wave * 4 + i;            // 0..15
      const int row = g8 * 8 + lr8;            // 0..127
      async_ld16(&A[(size_t)(m0 + row) * K + k0 + lg * 8], &As[g8 * 512]);
    }
    // B: 2 issues/wave
#pragma unroll
    for (int i = 0; i < 2; ++i) {
      const int g8  = wave * 2 + i;            // 0..7
      const int row = g8 * 8 + lr8;            // 0..63
      async_ld16(&Bt[(size_t)(n0 + row) * K + k0 + lg * 8], &Bs[g8 * 512]);
    }
    __syncthreads();
#pragma unroll
    for (int h = 0; h < 2; ++h) {
      const int cs = h * 4 + qd;               // wanted chunk 0..7
      short8 af[4], bfr[2];
#pragma unroll
      for (int t = 0; t < 4; ++t) {
        const int r = wm + t * 16 + md;        // r&7 == md&7
        af[t] = *(const short8*)&As[r * 64 + ((cs ^ mS) << 3)];
      }
#pragma unroll
      for (int t = 0; t < 2; ++t) {
        const int r = wn + t * 16 + md;
        bfr[t] = *(const short8*)&Bs[r * 64 + ((cs ^ mS) << 3)];
      }
#pragma unroll
      for (int i = 0; i < 4; ++i)
#pragma unroll
        for (int j = 0; j < 2; ++j)
          acc[i][j] = __builtin_amdgcn_mfma_f32_16x16x32_bf16(bfr[j], af[i], acc[i][j], 0, 0, 0);
    }
    __syncthreads();
  }

  // transposed: lane holds orig row = m0+wm+i*16+md, cols = n0+wn+j*16+qd*4..+3
  const int bbase = b0 + ((m0 + wm) >> 5);
  const size_t bNH0 = (size_t)bbase * NH, bNH1 = bNH0 + NH;
  float4 dqA[2], dqB[2], ggA[2], ggB[2];
#pragma unroll
  for (int j = 0; j < 2; ++j) {
    const int colb = n0 + wn + j * 16 + (qd << 2);
    dqA[j] = *(const float4*)&dvec[bNH0 + colb];
    dqB[j] = *(const float4*)&dvec[bNH1 + colb];
    if constexpr (EPI == 2) {
      ggA[j] = *(const float4*)&gvec[bNH0 + colb];
      ggB[j] = *(const float4*)&gvec[bNH1 + colb];
    }
  }
#pragma unroll
  for (int i = 0; i < 4; ++i) {
    const int rowg = m0 + wm + i * 16 + md;
    const int j2 = rowg & 31;
#pragma unroll
    for (int j = 0; j < 2; ++j) {
      const int colb = n0 + wn + j * 16 + (qd << 2);
      const short4v wq = *(const short4v*)&wepiT[(size_t)j2 * NH + colb];
      const float4 dq = (i < 2) ? dqA[j] : dqB[j];
      const float dqv[4] = {dq.x, dq.y, dq.z, dq.w};
      float v[4];
      short4v o1v;
#pragma unroll
      for (int r = 0; r < 4; ++r) {
        v[r] = acc[i][j][r] * scale + bf2f(wq[r]);
        o1v[r] = f2bf(v[r] * dqv[r]);
      }
      *(short4v*)&o1[(size_t)rowg * NH + colb] = o1v;
      if constexpr (EPI == 2) {
        const float4 gg = (i < 2) ? ggA[j] : ggB[j];
        const float ggv[4] = {gg.x, gg.y, gg.z, gg.w};
        short4v o2v;
#pragma unroll
        for (int r = 0; r < 4; ++r) o2v[r] = f2bf(v[r] * ggv[r]);
        *(short4v*)&o2[(size_t)rowg * NH + colb] = o2v;
      }
    }
  }
}

// ---------------- bf16 MFMA GEMM, 64x64 tile, K-split partials (z=2, forward) ----------------
__global__ __launch_bounds__(256) void k_mgemm64s(
    const short* __restrict__ A, const short* __restrict__ Bt,
    float* __restrict__ Cpart)
{
  __shared__ short As[64 * 32];
  __shared__ short Bs[64 * 32];
  const int tid  = threadIdx.x;
  const int wave = tid >> 6, lane = tid & 63;
  const int m0 = blockIdx.x << 6, n0 = blockIdx.y << 6;   // XCD swizzle
  const int kb = blockIdx.z << 9;                          // 0 or 512
  const int wm = (wave >> 1) << 5, wn = (wave & 1) << 5;
  const int qd = lane >> 4, md = lane & 15;
  const int sr = lane >> 2;
  const int sc = (lane & 3) << 3;

  float4v acc[2][2];
#pragma unroll
  for (int i = 0; i < 2; ++i)
#pragma unroll
    for (int j = 0; j < 2; ++j) acc[i][j] = (float4v)(0.f);

  for (int k0 = kb; k0 < kb + 512; k0 += 32) {
    const int row = wave * 16 + sr;
    async_ld16(&A [(size_t)(m0 + row) * NH + k0 + sc], &As[wave * 512]);
    async_ld16(&Bt[(size_t)(n0 + row) * NH + k0 + sc], &Bs[wave * 512]);
    __syncthreads();
    short8 af[2], bfr[2];
#pragma unroll
    for (int t = 0; t < 2; ++t) {
      af[t]  = *(const short8*)&As[(wm + t * 16 + md) * 32 + qd * 8];
      bfr[t] = *(const short8*)&Bs[(wn + t * 16 + md) * 32 + qd * 8];
    }
#pragma unroll
    for (int i = 0; i < 2; ++i)
#pragma unroll
      for (int j = 0; j < 2; ++j)
        acc[i][j] = __builtin_amdgcn_mfma_f32_16x16x32_bf16(bfr[j], af[i], acc[i][j], 0, 0, 0);
    __syncthreads();
  }

  float* out = Cpart + (size_t)blockIdx.z * NB * NH;
#pragma unroll
  for (int i = 0; i < 2; ++i) {
    const int rowg = m0 + wm + i * 16 + md;
#pragma unroll
    for (int j = 0; j < 2; ++j) {
      const int colb = n0 + wn + j * 16 + (qd << 2);
      float4 o;
      o.x = acc[i][j][0]; o.y = acc[i][j][1];
      o.z = acc[i][j][2]; o.w = acc[i][j][3];
      *reinterpret_cast<float4*>(&out[(size_t)rowg * NH + colb]) = o;
    }
  }
}

// ---------------- bf16 MFMA GEMM, 64x64 tile, fused backward epilogues (unsplit) ----------------
// FEPI 3 (bw1): t=acc*scale; ob=bf16(t*auxA), of1=sqrt(max(t*auxB,0))   [E1b, SD1]
// FEPI 4 (bw0): t=acc*scale; ob=bf16(t*auxA), of1=t*auxB               [GT0b, D0]
template<int FEPI>
__global__ __launch_bounds__(256) void k_mgemm64f(
    const short* __restrict__ A, const short* __restrict__ Bt,
    const float* __restrict__ auxA, const float* __restrict__ auxB,
    short* __restrict__ ob, float* __restrict__ of1,
    float scale)
{
  __shared__ short As[64 * 32];
  __shared__ short Bs[64 * 32];
  const int tid  = threadIdx.x;
  const int wave = tid >> 6, lane = tid & 63;
  const int m0 = blockIdx.x << 6, n0 = blockIdx.y << 6;
  const int wm = (wave >> 1) << 5, wn = (wave & 1) << 5;
  const int qd = lane >> 4, md = lane & 15;
  const int sr = lane >> 2;
  const int sc = (lane & 3) << 3;

  float4v acc[2][2];
#pragma unroll
  for (int i = 0; i < 2; ++i)
#pragma unroll
    for (int j = 0; j < 2; ++j) acc[i][j] = (float4v)(0.f);

  for (int k0 = 0; k0 < NH; k0 += 32) {
    const int row = wave * 16 + sr;
    async_ld16(&A [(size_t)(m0 + row) * NH + k0 + sc], &As[wave * 512]);
    async_ld16(&Bt[(size_t)(n0 + row) * NH + k0 + sc], &Bs[wave * 512]);
    __syncthreads();
    short8 af[2], bfr[2];
#pragma unroll
    for (int t = 0; t < 2; ++t) {
      af[t]  = *(const short8*)&As[(wm + t * 16 + md) * 32 + qd * 8];
      bfr[t] = *(const short8*)&Bs[(wn + t * 16 + md) * 32 + qd * 8];
    }
#pragma unroll
    for (int i = 0; i < 2; ++i)
#pragma unroll
      for (int j = 0; j < 2; ++j)
        acc[i][j] = __builtin_amdgcn_mfma_f32_16x16x32_bf16(bfr[j], af[i], acc[i][j], 0, 0, 0);
    __syncthreads();
  }

#pragma unroll
  for (int i = 0; i < 2; ++i) {
    const int rowg = m0 + wm + i * 16 + md;
#pragma unroll
    for (int j = 0; j < 2; ++j) {
      const int colb = n0 + wn + j * 16 + (qd << 2);
      const size_t oi = (size_t)rowg * NH + colb;
      const float4 g4 = *(const float4*)&auxA[oi];
      const float4 u4 = *(const float4*)&auxB[oi];
      const float gv[4] = {g4.x, g4.y, g4.z, g4.w};
      const float uv[4] = {u4.x, u4.y, u4.z, u4.w};
      short4v eb;
      float sd[4];
#pragma unroll
      for (int r = 0; r < 4; ++r) {
        const float t = acc[i][j][r] * scale;
        eb[r] = f2bf(t * gv[r]);
        if constexpr (FEPI == 3) sd[r] = sqrtf(fmaxf(t * uv[r], 0.f));
        else                     sd[r] = t * uv[r];
      }
      *(short4v*)&ob[oi] = eb;
      float4 s4; s4.x = sd[0]; s4.y = sd[1]; s4.z = sd[2]; s4.w = sd[3];
      *(float4*)&of1[oi] = s4;
    }
  }
}

// ---------------- activation (layer 1): sum HP halves, writes Zbf, G, U ----------------
__global__ __launch_bounds__(256) void k_act(
    const float* __restrict__ HP2, const float* __restrict__ HPC_l,
    const float* __restrict__ bA, const float* __restrict__ bB,
    const float* __restrict__ bC,
    const float* __restrict__ anb, const float* __restrict__ anl,
    short* __restrict__ Zbf, float* __restrict__ G, float* __restrict__ U,
    float scale)
{
  const int idx = blockIdx.x * 256 + threadIdx.x;
  const int i = idx & 1023;
  const float bias = bA[i] + bB[i] + bC[i] + anb[i];
  const float el = expf(anl[i]);
  const float hc = HPC_l[(size_t)(idx >> 10) * (3 * NH) + i];
  const float hp = (HP2[idx] + HP2[(size_t)NB * NH + idx]) * scale;
  const float a = (hp + hc + bias) * el;
  const float pdf = expf(-0.5f * a * a);
  const float er = erff(a * SQRT_HALF);
  Zbf[idx] = f2bf((SQRT_HPI * a * er + pdf + SQRT_HPI * a) * INV_SQRT2PI);
  G[idx] = 0.5f * (1.f + er) * el;
  U[idx] = pdf * INV_SQRT2PI * el * el;
}

// ---------------- activation (layer 2): SD2 = sqrt(t2*u2), D2g bf16 ----------------
__global__ __launch_bounds__(256) void k_act2(
    const float* __restrict__ HP2, const float* __restrict__ HPC_l,
    const float* __restrict__ bA, const float* __restrict__ bB,
    const float* __restrict__ bC,
    const float* __restrict__ anb, const float* __restrict__ anl,
    const float* __restrict__ so,
    float* __restrict__ SD2, short* __restrict__ D2gbf, float scale)
{
  const int idx = blockIdx.x * 256 + threadIdx.x;
  const int i = idx & 1023;
  const float bias = bA[i] + bB[i] + bC[i] + anb[i];
  const float el = expf(anl[i]);
  const float hc = HPC_l[(size_t)(idx >> 10) * (3 * NH) + i];
  const float hp = (HP2[idx] + HP2[(size_t)NB * NH + idx]) * scale;
  const float a = (hp + hc + bias) * el;
  const float pdf = expf(-0.5f * a * a);
  const float er = erff(a * SQRT_HALF);
  const float g = 0.5f * (1.f + er) * el;
  const float u = pdf * INV_SQRT2PI * el * el;
  const float t2 = so[i] * (1.f / NH);
  SD2[idx] = sqrtf(fmaxf(t2 * u, 0.f));
  D2gbf[idx] = f2bf(t2 * g);
}

// ---------------- Ah1[r,p] = bf16(G0[b,p] * W0T[j,p]) (coalesced) ----------------
__global__ __launch_bounds__(256) void k_scale0(
    const float* __restrict__ G0, const short* __restrict__ W0Tb,
    short* __restrict__ Ah1, int b0)
{
  const int idx = blockIdx.x * 256 + threadIdx.x;
  const int p = idx & 1023, r = idx >> 10;
  const int b = b0 + (r >> 5), j = r & 31;
  Ah1[idx] = f2bf(G0[(size_t)b * NH + p] * bf2f(W0Tb[(size_t)j * NH + p]));
}

// ---------------- f-GEMM: MFMA partials of [NB,NH]@[NH,32] per term/k-split ----------------
__global__ __launch_bounds__(256) void k_fgemm(
    const short* __restrict__ A0, const short* __restrict__ A1,
    const short* __restrict__ A2,
    const short* __restrict__ W0T, const short* __restrict__ W1T,
    const short* __restrict__ W2T,
    float* __restrict__ partF)
{
  const int mb = blockIdx.x;
  const int ks = blockIdx.y;
  const int term = blockIdx.z;
  const short* A  = (term == 0) ? A0 : (term == 1) ? A1 : A2;
  const short* WT = (term == 0) ? W0T : (term == 1) ? W1T : W2T;
  const int wave = threadIdx.x >> 6, lane = threadIdx.x & 63;
  const int qd = lane >> 4, md = lane & 15;
  const int m0 = mb * 128 + wave * 32;
  const int kbeg = ks * (NH / KSF);

  float4v acc[2][2];
#pragma unroll
  for (int i = 0; i < 2; ++i)
#pragma unroll
    for (int j = 0; j < 2; ++j) acc[i][j] = (float4v)(0.f);

  for (int k0 = kbeg; k0 < kbeg + NH / KSF; k0 += 32) {
    const int kk = k0 + qd * 8;
    short8 af[2], bfr[2];
    af[0]  = *(const short8*)&A[(size_t)(m0 + md) * NH + kk];
    af[1]  = *(const short8*)&A[(size_t)(m0 + 16 + md) * NH + kk];
    bfr[0] = *(const short8*)&WT[(size_t)md * NH + kk];
    bfr[1] = *(const short8*)&WT[(size_t)(16 + md) * NH + kk];
#pragma unroll
    for (int i = 0; i < 2; ++i)
#pragma unroll
      for (int j = 0; j < 2; ++j)
        acc[i][j] = __builtin_amdgcn_mfma_f32_16x16x32_bf16(af[i], bfr[j], acc[i][j], 0, 0, 0);
  }

  float* out = &partF[(size_t)(term * KSF + ks) * NB * 32];
#pragma unroll
  for (int i = 0; i < 2; ++i)
#pragma unroll
    for (int j = 0; j < 2; ++j)
#pragma unroll
      for (int r = 0; r < 4; ++r) {
        const int row = m0 + i * 16 + qd * 4 + r;
        const int col = j * 16 + md;
        out[(size_t)row * 32 + col] = acc[i][j][r];
      }
}

// ---------------- reduce f partials + epilogue ----------------
__global__ __launch_bounds__(256) void k_fred(
    const float* __restrict__ partF, const float* __restrict__ X,
    const float* __restrict__ Wxout,
    const float* __restrict__ w0p, const float* __restrict__ w1p,
    float* __restrict__ outF)
{
  const int e = blockIdx.x * 256 + threadIdx.x;
  float s = 0.f;
#pragma unroll
  for (int p = 0; p < 3 * KSF; ++p) s += partF[(size_t)p * NB * 32 + e];
  const float spw0 = sp_f(w0p[0]);
  const float spw1 = sp_f(w1p[0]);
  outF[e] = spw1 * (s + Wxout[e & 31]) + spw0 * X[e];
}

// ---------------- K-split per-sample Gram partials ----------------
__global__ __launch_bounds__(256) void k_gram(
    const short* __restrict__ Q1, const short* __restrict__ Q2,
    const short* __restrict__ W0T, const float* __restrict__ D0,
    float* __restrict__ partH, int b0)
{
  const int ns = blockIdx.x, bl = blockIdx.y;
  const int b = b0 + bl;
  const int wave = threadIdx.x >> 6, lane = threadIdx.x & 63;
  const int wm = (wave >> 1) << 4, wn = (wave & 1) << 4;
  const int qd = lane >> 4, md = lane & 15;
  const int kbeg = ns << 7;
  const size_t rb = (size_t)bl * 32 * NH;

  float4v acc = (float4v)(0.f);

  for (int k0 = kbeg; k0 < kbeg + 128; k0 += 32) {
    const int kk = k0 + qd * 8;
    const short8 ar = *(const short8*)&W0T[(size_t)(wm + md) * NH + kk];
    float dd[8];
    *(float4*)&dd[0] = *(const float4*)&D0[(size_t)b * NH + kk];
    *(float4*)&dd[4] = *(const float4*)&D0[(size_t)b * NH + kk + 4];
    short8 af;
#pragma unroll
    for (int e = 0; e < 8; ++e) af[e] = f2bf(bf2f(ar[e]) * dd[e]);
    const short8 bfr = *(const short8*)&W0T[(size_t)(wn + md) * NH + kk];
    acc = __builtin_amdgcn_mfma_f32_16x16x32_bf16(af, bfr, acc, 0, 0, 0);
  }
#pragma unroll
  for (int l = 0; l < 2; ++l) {
    const short* Q = (l == 0) ? Q1 : Q2;
    for (int k0 = kbeg; k0 < kbeg + 128; k0 += 32) {
      const int kk = k0 + qd * 8;
      const short8 af  = *(const short8*)&Q[rb + (size_t)(wm + md) * NH + kk];
      const short8 bfr = *(const short8*)&Q[rb + (size_t)(wn + md) * NH + kk];
      acc = __builtin_amdgcn_mfma_f32_16x16x32_bf16(af, bfr, acc, 0, 0, 0);
    }
  }

  float* out = &partH[((size_t)bl * NS + ns) * 1024];
#pragma unroll
  for (int r = 0; r < 4; ++r)
    out[(wm + qd * 4 + r) * 32 + (wn + md)] = acc[r];
}

// ---------------- reduce partials + Cholesky logdet ----------------
__global__ __launch_bounds__(256) void k_gram2(
    const float* __restrict__ partH,
    const float* __restrict__ w0p, const float* __restrict__ w1p,
    float* __restrict__ outLD, int b0)
{
  const int bl = blockIdx.x, b = b0 + bl, tid = threadIdx.x;
  __shared__ float sH[32][33];
  __shared__ float sred[32];
  const float spw0 = sp_f(w0p[0]);
  const float spw1 = sp_f(w1p[0]);
  const float* base = &partH[(size_t)bl * NS * 1024];
#pragma unroll
  for (int r = 0; r < 4; ++r) {
    const int e = r * 256 + tid;
    float s = 0.f;
#pragma unroll
    for (int ns = 0; ns < NS; ++ns) s += base[ns * 1024 + e];
    float h = s * spw1;
    const int row = e >> 5, col = e & 31;
    if (row == col) h += spw0;
    sH[row][col] = h;
  }
  __syncthreads();

  float ldacc = 0.f;
  for (int c = 0; c < 32; ++c) {
    if (tid >= c && tid < 32) {
      float s = sH[tid][c];
      for (int m = 0; m < c; ++m) s -= sH[tid][m] * sH[c][m];
      sred[tid] = s;
    }
    __syncthreads();
    const float sc = sred[c];
    if (tid >= c && tid < 32) {
      const float lcc = sqrtf(sc);
      sH[tid][c] = (tid == c) ? lcc : sred[tid] / lcc;
    }
    ldacc += logf(sc);
    __syncthreads();
  }
  if (tid == 0) outLD[b] = ldacc;
}

// ---------------- launcher ----------------
extern "C" void kernel_launch(void* const* d_in, const int* in_sizes, int n_in,
                              void* d_out, int out_size, void* d_ws, size_t ws_size,
                              hipStream_t stream)
{
  const float* X    = (const float*)d_in[0];
  const float* Cc   = (const float*)d_in[1];
  const float* w0   = (const float*)d_in[2];
  const float* w1   = (const float*)d_in[3];
  const float* Wz0w = (const float*)d_in[4];
  const float* Wz0b = (const float*)d_in[5];
  const float* Wc0w = (const float*)d_in[6];
  const float* Wc0b = (const float*)d_in[7];
  const float* an0b = (const float*)d_in[8];
  const float* an0l = (const float*)d_in[9];
  const float* Wz1w = (const float*)d_in[10];
  const float* Wz1b = (const float*)d_in[11];
  const float* Wx1w = (const float*)d_in[12];
  const float* Wx1b = (const float*)d_in[13];
  const float* Wc1w = (const float*)d_in[14];
  const float* Wc1b = (const float*)d_in[15];
  const float* an1b = (const float*)d_in[16];
  const float* an1l = (const float*)d_in[17];
  const float* Wz2w = (const float*)d_in[18];
  const float* Wz2b = (const float*)d_in[19];
  const float* Wx2w = (const float*)d_in[20];
  const float* Wx2b = (const float*)d_in[21];
  const float* Wc2w = (const float*)d_in[22];
  const float* Wc2b = (const float*)d_in[23];
  const float* an2b = (const float*)d_in[24];
  const float* an2l = (const float*)d_in[25];
  const float* Wzoutw = (const float*)d_in[26];
  const float* Wxoutw = (const float*)d_in[27];
  // d_in[28] (Wcout_w): constant in x -> no grad/Hessian contribution.

  float* ws = (float*)d_ws;
  size_t off = 0;
  auto alloc = [&](size_t n) {
    float* p = ws + off; off += (n + 3) & ~(size_t)3; return p;
  };
  const size_t HH = (size_t)NH * NH;
  const size_t BH = (size_t)NB * NH;

  short* S1b  = (short*)alloc(HH / 2);
  short* S2b  = (short*)alloc(HH / 2);
  short* S1Tb = (short*)alloc(HH / 2);
  short* S2Tb = (short*)alloc(HH / 2);
  short* Wc0bb = (short*)alloc((size_t)NH * NC / 2);
  short* Wc1bb = (short*)alloc((size_t)NH * NC / 2);
  short* Wc2bb = (short*)alloc((size_t)NH * NC / 2);
  short* Ccb  = (short*)alloc((size_t)NB * NC / 2);
  short* W0Tb = (short*)alloc((size_t)NDIM * NH / 2);
  short* Wx1Tb = (short*)alloc((size_t)NDIM * NH / 2);
  short* Wx2Tb = (short*)alloc((size_t)NDIM * NH / 2);
  float* so   = alloc(NH);
  float* HP2  = alloc(2 * BH);                // K-split GEMM partials
  float* HPC  = alloc((size_t)NB * 3 * NH);   // c-path + X-terms [NB, 3*NH]
  short* Z0b  = (short*)alloc(BH / 2);
  short* Z1b  = (short*)alloc(BH / 2);
  float* G0   = alloc(BH);
  float* U0   = alloc(BH);
  float* G1   = alloc(BH);
  float* U1   = alloc(BH);
  float* SD2  = alloc(BH);
  short* D2gb = (short*)alloc(BH / 2);
  short* E1b  = (short*)alloc(BH / 2);
  float* SD1  = alloc(BH);
  float* D0   = alloc(BH);
  short* GT0b = (short*)alloc(BH / 2);
  float* partF = alloc((size_t)3 * KSF * NB * 32);

  // chunk buffers: Ah1, A2, Q1 (bf16); Q2 aliases Ah1 (dead after GEMM1)
  const size_t avail_f = ws_size / sizeof(float);
  int CB = 32;
  const int cands[6] = {1024, 512, 256, 128, 64, 32};
  for (int ci = 0; ci < 6; ++ci) {
    const size_t need = off + 3 * ((size_t)cands[ci] * 32 * NH / 2 + 4)
                      + (size_t)cands[ci] * NS * 1024 + 64;
    if (need <= avail_f) { CB = cands[ci]; break; }
  }
  const size_t chunk_sh = (size_t)CB * 32 * NH;
  short* Ah1 = (short*)alloc(chunk_sh / 2);
  short* A2b = (short*)alloc(chunk_sh / 2);
  short* Q1b = (short*)alloc(chunk_sh / 2);
  short* Q2b = Ah1;
  float* partH = alloc((size_t)CB * NS * 1024);

  float* outF  = (float*)d_out;
  float* outLD = (float*)d_out + NB * NDIM;

  const dim3 blk2(16, 16);
  const dim3 gridXz(16, NB / 64, 3);        // fused X-terms (+ act0 in z=0)
  const dim3 gridE(NB * NH / 256);
  const dim3 grid64s(NB / 64, NH / 64, 2);  // K-split 64-tile mfma (512 blocks)
  const dim3 grid64u(NB / 64, NH / 64);     // unsplit fused-backward 64-tile
  const dim3 gridC(NB / 128, 3 * NH / 128); // fused c-GEMM
  const float invH = 1.0f / (float)NH;

  k_prep<<<dim3(HH / 256), dim3(256), 0, stream>>>(
      Wz1w, Wz2w, Wzoutw, Wz0w, Wx1w, Wx2w, Wc0w, Wc1w, Wc2w, Cc,
      S1b, S1Tb, S2b, S2Tb, Wc0bb, Wc1bb, Wc2bb, Ccb, W0Tb, Wx1Tb, Wx2Tb, so);

  // HPC = c-path (bf16 MFMA), then X-terms (fp32) with fused layer-0 activation (z=0)
  k_m128<<<gridC, dim3(256), 0, stream>>>(Ccb, Wc0bb, HPC, 1.f, NC, 3 * NH);
  k_gemmx<<<gridXz, blk2, 0, stream>>>(X, Wz0w, Wx1w, Wx2w,
                                       HPC + 0 * NH, HPC + 1 * NH, HPC + 2 * NH, 3 * NH,
                                       Wz0b, Wc0b, an0b, an0l, Z0b, G0, U0);

  // layer 1
  k_mgemm64s<<<grid64s, dim3(256), 0, stream>>>(Z0b, S1b, HP2);
  k_act<<<gridE, dim3(256), 0, stream>>>(HP2, HPC + 1 * NH, Wz1b, Wx1b, Wc1b,
                                         an1b, an1l, Z1b, G1, U1, invH);
  // layer 2
  k_mgemm64s<<<grid64s, dim3(256), 0, stream>>>(Z1b, S2b, HP2);
  k_act2<<<gridE, dim3(256), 0, stream>>>(HP2, HPC + 2 * NH, Wz2b, Wx2b, Wc2b,
                                          an2b, an2l, so, SD2, D2gb, invH);
  // backward sensitivities (fused epilogues, unsplit)
  k_mgemm64f<3><<<grid64u, dim3(256), 0, stream>>>(D2gb, S2Tb, G1, U1, E1b, SD1, invH);
  k_mgemm64f<4><<<grid64u, dim3(256), 0, stream>>>(E1b, S1Tb, G0, U0, GT0b, D0, invH);

  // f (grad) via MFMA partials + reduce
  k_fgemm<<<dim3(8, KSF, 3), dim3(256), 0, stream>>>(
      GT0b, E1b, D2gb, W0Tb, Wx1Tb, Wx2Tb, partF);
  k_fred<<<dim3(NB * 32 / 256), dim3(256), 0, stream>>>(
      partF, X, Wxoutw, w0, w1, outF);

  // Jacobian propagation + K-split Gram + Cholesky, chunked over samples
  const dim3 gridJ(CB * 32 / 128, NH / 64);    // 128x64 tile (x = M-block, XCD swizzle)
  const dim3 gridS((size_t)CB * 32 * NH / 256);
  const dim3 gridG(NS, CB);
  for (int b0 = 0; b0 < NB; b0 += CB) {
    k_scale0<<<gridS, dim3(256), 0, stream>>>(G0, W0Tb, Ah1, b0);
    k_mgemm<2><<<gridJ, dim3(256), 0, stream>>>(Ah1, S1b, Q1b, A2b,
                                                G1, SD1, Wx1Tb, invH, NH, b0);
    k_mgemm<1><<<gridJ, dim3(256), 0, stream>>>(A2b, S2b, Q2b, nullptr,
                                                nullptr, SD2, Wx2Tb, invH, NH, b0);
    k_gram<<<gridG, dim3(256), 0, stream>>>(Q1b, Q2b, W0Tb, D0, partH, b0);
    k_gram2<<<dim3(CB), dim3(256), 0, stream>>>(partH, w0, w1, outLD, b0);
  }
}

// Round 14
// 643.175 us; speedup vs baseline: 1.2313x; 1.0078x over previous
//
#include <hip/hip_runtime.h>

constexpr int NB   = 1024;  // batch
constexpr int NDIM = 32;    // x dim
constexpr int NH   = 1024;  // hidden dim
constexpr int NC   = 512;   // context dim
constexpr int NS   = 8;     // K-splits in k_gram
constexpr int KSF  = 8;     // K-splits per term in k_fgemm

constexpr float INV_SQRT2PI = 0.3989422804014327f;
constexpr float SQRT_HALF   = 0.70710678118654752f;
constexpr float SQRT_HPI    = 1.2533141373155003f;

typedef __attribute__((ext_vector_type(8))) short short8;
typedef __attribute__((ext_vector_type(4))) short short4v;
typedef __attribute__((ext_vector_type(4))) float float4v;

__device__ __forceinline__ float sp_f(float x) {
  return (x > 20.f) ? x : log1pf(expf(x));
}

__device__ __forceinline__ short f2bf(float f) {
  union { float f; unsigned u; } x; x.f = f;
  const unsigned r = x.u + 0x7fffu + ((x.u >> 16) & 1u);
  return (short)(r >> 16);
}

__device__ __forceinline__ float bf2f(short s) {
  union { unsigned u; float f; } c;
  c.u = ((unsigned)(unsigned short)s) << 16;
  return c.f;
}

__device__ __forceinline__ void async_ld16(const void* g, void* l) {
  __builtin_amdgcn_global_load_lds(
      (const __attribute__((address_space(1))) void*)g,
      (__attribute__((address_space(3))) void*)l, 16, 0, 0);
}

// ---------------- prep ----------------
__global__ __launch_bounds__(256) void k_prep(
    const float* __restrict__ Wz1, const float* __restrict__ Wz2,
    const float* __restrict__ Wzout, const float* __restrict__ Wz0,
    const float* __restrict__ Wx1, const float* __restrict__ Wx2,
    const float* __restrict__ Wc0, const float* __restrict__ Wc1,
    const float* __restrict__ Wc2, const float* __restrict__ Cc,
    short* __restrict__ S1b, short* __restrict__ S1Tb,
    short* __restrict__ S2b, short* __restrict__ S2Tb,
    short* __restrict__ Wc0b, short* __restrict__ Wc1b, short* __restrict__ Wc2b,
    short* __restrict__ Ccb, short* __restrict__ W0Tb,
    short* __restrict__ Wx1Tb, short* __restrict__ Wx2Tb,
    float* __restrict__ so)
{
  const int idx = blockIdx.x * 256 + threadIdx.x;   // 0 .. NH*NH-1
  const int i = idx >> 10, p = idx & 1023;
  const float v1 = sp_f(Wz1[idx]);
  const short b1 = f2bf(v1);
  S1b[idx] = b1; S1Tb[p * NH + i] = b1;
  const float v2 = sp_f(Wz2[idx]);
  const short b2 = f2bf(v2);
  S2b[idx] = b2; S2Tb[p * NH + i] = b2;
  if (idx < NH) so[idx] = sp_f(Wzout[idx]);
  if (idx < NH * NC) {
    Wc0b[idx] = f2bf(Wc0[idx]);
    Wc1b[idx] = f2bf(Wc1[idx]);
    Wc2b[idx] = f2bf(Wc2[idx]);
  }
  if (idx < NB * NC) Ccb[idx] = f2bf(Cc[idx]);
  if (idx < NDIM * NH) {
    const int j = idx >> 10, pp = idx & 1023;   // out [32,1024]
    W0Tb[idx]  = f2bf(Wz0[pp * NDIM + j]);
    Wx1Tb[idx] = f2bf(Wx1[pp * NDIM + j]);
    Wx2Tb[idx] = f2bf(Wx2[pp * NDIM + j]);
  }
}

// ---------------- fp32 tiled GEMM, 3 X-terms in one dispatch; z=0 fuses layer-0 act ----------------
__global__ __launch_bounds__(256) void k_gemmx(
    const float* __restrict__ A,
    const float* __restrict__ B0, const float* __restrict__ B1,
    const float* __restrict__ B2,
    float* __restrict__ C0, float* __restrict__ C1, float* __restrict__ C2,
    int ldc,
    const float* __restrict__ bz0, const float* __restrict__ bc0,
    const float* __restrict__ anb0, const float* __restrict__ anl0,
    short* __restrict__ Z0b, float* __restrict__ G0, float* __restrict__ U0)
{
  const float* Bt = (blockIdx.z == 0) ? B0 : (blockIdx.z == 1) ? B1 : B2;
  float* C        = (blockIdx.z == 0) ? C0 : (blockIdx.z == 1) ? C1 : C2;
  __shared__ float As[16][68];
  __shared__ float Bs[16][68];
  const int tid  = threadIdx.y * 16 + threadIdx.x;
  const int arow = tid >> 2;
  const int acol = (tid & 3) << 2;
  const int m0 = blockIdx.y << 6;
  const int n0 = blockIdx.x << 6;

  float acc[4][4];
#pragma unroll
  for (int i = 0; i < 4; ++i)
#pragma unroll
    for (int j = 0; j < 4; ++j) acc[i][j] = 0.f;

  const int R = m0 + arow;
  for (int k0 = 0; k0 < NDIM; k0 += 16) {
    const float4 av = *reinterpret_cast<const float4*>(&A[(size_t)R * NDIM + k0 + acol]);
    As[acol + 0][arow] = av.x; As[acol + 1][arow] = av.y;
    As[acol + 2][arow] = av.z; As[acol + 3][arow] = av.w;
    const float4 bv = *reinterpret_cast<const float4*>(&Bt[(size_t)(n0 + arow) * NDIM + k0 + acol]);
    Bs[acol + 0][arow] = bv.x; Bs[acol + 1][arow] = bv.y;
    Bs[acol + 2][arow] = bv.z; Bs[acol + 3][arow] = bv.w;
    __syncthreads();
#pragma unroll
    for (int kk = 0; kk < 16; ++kk) {
      const float4 a  = *reinterpret_cast<const float4*>(&As[kk][threadIdx.y << 2]);
      const float4 bb = *reinterpret_cast<const float4*>(&Bs[kk][threadIdx.x << 2]);
      const float am[4] = {a.x, a.y, a.z, a.w};
      const float bn[4] = {bb.x, bb.y, bb.z, bb.w};
#pragma unroll
      for (int i2 = 0; i2 < 4; ++i2)
#pragma unroll
        for (int j2 = 0; j2 < 4; ++j2)
          acc[i2][j2] = fmaf(am[i2], bn[j2], acc[i2][j2]);
    }
    __syncthreads();
  }
#pragma unroll
  for (int i2 = 0; i2 < 4; ++i2) {
    const int row = m0 + (threadIdx.y << 2) + i2;
    const int col = n0 + (threadIdx.x << 2);
    float* cp = &C[(size_t)row * ldc + col];
    const float4 cur = *reinterpret_cast<const float4*>(cp);
    float o[4];
    o[0] = acc[i2][0] + cur.x; o[1] = acc[i2][1] + cur.y;
    o[2] = acc[i2][2] + cur.z; o[3] = acc[i2][3] + cur.w;
    if (blockIdx.z == 0) {
      short4v zb;
      float4 g4, u4;
      float gg[4], uu[4];
#pragma unroll
      for (int e = 0; e < 4; ++e) {
        const int cc = col + e;
        const float bias = bz0[cc] + bc0[cc] + anb0[cc];
        const float el = expf(anl0[cc]);
        const float a = (o[e] + bias) * el;
        const float pdf = expf(-0.5f * a * a);
        const float er = erff(a * SQRT_HALF);
        zb[e] = f2bf((SQRT_HPI * a * er + pdf + SQRT_HPI * a) * INV_SQRT2PI);
        gg[e] = 0.5f * (1.f + er) * el;
        uu[e] = pdf * INV_SQRT2PI * el * el;
      }
      const size_t oi = (size_t)row * NH + col;
      *(short4v*)&Z0b[oi] = zb;
      g4.x = gg[0]; g4.y = gg[1]; g4.z = gg[2]; g4.w = gg[3];
      u4.x = uu[0]; u4.y = uu[1]; u4.z = uu[2]; u4.w = uu[3];
      *(float4*)&G0[oi] = g4;
      *(float4*)&U0[oi] = u4;
    } else {
      float4 ov;
      ov.x = o[0]; ov.y = o[1]; ov.z = o[2]; ov.w = o[3];
      *reinterpret_cast<float4*>(cp) = ov;
    }
  }
}

// ---------------- bf16 MFMA GEMM, 128x128 tile, fp32 out (c-path), transposed tiles ----------------
__global__ __launch_bounds__(256) void k_m128(
    const short* __restrict__ A, const short* __restrict__ Bt,
    float* __restrict__ C, float scale, int K, int ldc)
{
  __shared__ short As[128 * 32];
  __shared__ short Bs[128 * 32];
  const int tid  = threadIdx.x;
  const int wave = tid >> 6, lane = tid & 63;
  const int m0 = blockIdx.x << 7, n0 = blockIdx.y << 7;   // XCD swizzle
  const int wm = (wave >> 1) << 6, wn = (wave & 1) << 6;
  const int qd = lane >> 4, md = lane & 15;
  const int sr = lane >> 2;
  const int sc = (lane & 3) << 3;

  float4v acc[4][4];
#pragma unroll
  for (int i = 0; i < 4; ++i)
#pragma unroll
    for (int j = 0; j < 4; ++j) acc[i][j] = (float4v)(0.f);

  for (int k0 = 0; k0 < K; k0 += 32) {
#pragma unroll
    for (int i = 0; i < 2; ++i) {
      const int ch  = wave * 2 + i;
      const int row = ch * 16 + sr;
      async_ld16(&A [(size_t)(m0 + row) * K + k0 + sc], &As[ch * 512]);
      async_ld16(&Bt[(size_t)(n0 + row) * K + k0 + sc], &Bs[ch * 512]);
    }
    __syncthreads();
    short8 af[4], bfr[4];
#pragma unroll
    for (int t = 0; t < 4; ++t) {
      af[t]  = *(const short8*)&As[(wm + t * 16 + md) * 32 + qd * 8];
      bfr[t] = *(const short8*)&Bs[(wn + t * 16 + md) * 32 + qd * 8];
    }
#pragma unroll
    for (int i = 0; i < 4; ++i)
#pragma unroll
      for (int j = 0; j < 4; ++j)
        acc[i][j] = __builtin_amdgcn_mfma_f32_16x16x32_bf16(bfr[j], af[i], acc[i][j], 0, 0, 0);
    __syncthreads();
  }

#pragma unroll
  for (int i = 0; i < 4; ++i) {
    const int rowg = m0 + wm + i * 16 + md;
#pragma unroll
    for (int j = 0; j < 4; ++j) {
      const int colb = n0 + wn + j * 16 + (qd << 2);
      float4 o;
      o.x = acc[i][j][0] * scale; o.y = acc[i][j][1] * scale;
      o.z = acc[i][j][2] * scale; o.w = acc[i][j][3] * scale;
      *reinterpret_cast<float4*>(&C[(size_t)rowg * ldc + colb]) = o;
    }
  }
}

// ---------------- bf16 MFMA GEMM, 128x64 tile, BK=128 + XOR-swizzled LDS (Jacobian GEMMs) ----------------
// 16 chunks (16B) per row; chunk c of row r stored at slot c ^ (r&7). Staging permutes
// SOURCE addresses (LDS dests stay lane-contiguous: 16 chunks * 8 shorts = row stride).
// grid (CB*32/128, NH/64) — x = M-block (XCD locality on A). dvec PRE-SQRT'd.
// EPI 1: o1 = bf16((acc*scale + WxT) * dvec)                      [Q2]
// EPI 2: o1 = ..., o2 = bf16((acc*scale + WxT) * gvec)            [Q1, A2]
template<int EPI>
__global__ __launch_bounds__(256) void k_mgemm(
    const short* __restrict__ A, const short* __restrict__ Bt,
    short* __restrict__ o1, short* __restrict__ o2,
    const float* __restrict__ gvec, const float* __restrict__ dvec,
    const short* __restrict__ wepiT,
    float scale, int K, int b0)
{
  __shared__ short As[128 * 128];  // 32 KB
  __shared__ short Bs[64 * 128];   // 16 KB
  const int tid  = threadIdx.x;
  const int wave = tid >> 6, lane = tid & 63;
  const int m0 = blockIdx.x << 7, n0 = blockIdx.y << 6;   // 128 x 64 tile
  const int wm = (wave >> 1) << 6, wn = (wave & 1) << 5;  // wave: 64 x 32
  const int qd = lane >> 4, md = lane & 15;
  const int lr4 = lane >> 4;        // row-within-4 for staging (0..3)
  const int lc  = lane & 15;        // chunk slot (0..15)
  const int mS  = md & 7;           // read-side swizzle key

  float4v acc[4][2];
#pragma unroll
  for (int i = 0; i < 4; ++i)
#pragma unroll
    for (int j = 0; j < 2; ++j) acc[i][j] = (float4v)(0.f);

  for (int k0 = 0; k0 < K; k0 += 128) {
    // A: 8 issues/wave, each = 4 rows x 16 chunks (64 chunks, one per lane)
#pragma unroll
    for (int i = 0; i < 8; ++i) {
      const int g4  = wave * 8 + i;            // 0..31
      const int row = g4 * 4 + lr4;            // 0..127
      const int lg  = lc ^ (row & 7);          // swizzled source chunk
      async_ld16(&A[(size_t)(m0 + row) * K + k0 + lg * 8], &As[g4 * 512]);
    }
    // B: 4 issues/wave
#pragma unroll
    for (int i = 0; i < 4; ++i) {
      const int g4  = wave * 4 + i;            // 0..15
      const int row = g4 * 4 + lr4;            // 0..63
      const int lg  = lc ^ (row & 7);
      async_ld16(&Bt[(size_t)(n0 + row) * K + k0 + lg * 8], &Bs[g4 * 512]);
    }
    __syncthreads();
#pragma unroll
    for (int h = 0; h < 4; ++h) {
      const int cs = h * 4 + qd;               // wanted chunk 0..15
      short8 af[4], bfr[2];
#pragma unroll
      for (int t = 0; t < 4; ++t) {
        const int r = wm + t * 16 + md;        // r&7 == md&7
        af[t] = *(const short8*)&As[r * 128 + ((cs ^ mS) << 3)];
      }
#pragma unroll
      for (int t = 0; t < 2; ++t) {
        const int r = wn + t * 16 + md;
        bfr[t] = *(const short8*)&Bs[r * 128 + ((cs ^ mS) << 3)];
      }
#pragma unroll
      for (int i = 0; i < 4; ++i)
#pragma unroll
        for (int j = 0; j < 2; ++j)
          acc[i][j] = __builtin_amdgcn_mfma_f32_16x16x32_bf16(bfr[j], af[i], acc[i][j], 0, 0, 0);
    }
    __syncthreads();
  }

  // transposed: lane holds orig row = m0+wm+i*16+md, cols = n0+wn+j*16+qd*4..+3
  const int bbase = b0 + ((m0 + wm) >> 5);
  const size_t bNH0 = (size_t)bbase * NH, bNH1 = bNH0 + NH;
  float4 dqA[2], dqB[2], ggA[2], ggB[2];
#pragma unroll
  for (int j = 0; j < 2; ++j) {
    const int colb = n0 + wn + j * 16 + (qd << 2);
    dqA[j] = *(const float4*)&dvec[bNH0 + colb];
    dqB[j] = *(const float4*)&dvec[bNH1 + colb];
    if constexpr (EPI == 2) {
      ggA[j] = *(const float4*)&gvec[bNH0 + colb];
      ggB[j] = *(const float4*)&gvec[bNH1 + colb];
    }
  }
#pragma unroll
  for (int i = 0; i < 4; ++i) {
    const int rowg = m0 + wm + i * 16 + md;
    const int j2 = rowg & 31;
#pragma unroll
    for (int j = 0; j < 2; ++j) {
      const int colb = n0 + wn + j * 16 + (qd << 2);
      const short4v wq = *(const short4v*)&wepiT[(size_t)j2 * NH + colb];
      const float4 dq = (i < 2) ? dqA[j] : dqB[j];
      const float dqv[4] = {dq.x, dq.y, dq.z, dq.w};
      float v[4];
      short4v o1v;
#pragma unroll
      for (int r = 0; r < 4; ++r) {
        v[r] = acc[i][j][r] * scale + bf2f(wq[r]);
        o1v[r] = f2bf(v[r] * dqv[r]);
      }
      *(short4v*)&o1[(size_t)rowg * NH + colb] = o1v;
      if constexpr (EPI == 2) {
        const float4 gg = (i < 2) ? ggA[j] : ggB[j];
        const float ggv[4] = {gg.x, gg.y, gg.z, gg.w};
        short4v o2v;
#pragma unroll
        for (int r = 0; r < 4; ++r) o2v[r] = f2bf(v[r] * ggv[r]);
        *(short4v*)&o2[(size_t)rowg * NH + colb] = o2v;
      }
    }
  }
}

// ---------------- bf16 MFMA GEMM, 64x64 tile, K-split partials (z=2, forward) ----------------
__global__ __launch_bounds__(256) void k_mgemm64s(
    const short* __restrict__ A, const short* __restrict__ Bt,
    float* __restrict__ Cpart)
{
  __shared__ short As[64 * 32];
  __shared__ short Bs[64 * 32];
  const int tid  = threadIdx.x;
  const int wave = tid >> 6, lane = tid & 63;
  const int m0 = blockIdx.x << 6, n0 = blockIdx.y << 6;   // XCD swizzle
  const int kb = blockIdx.z << 9;                          // 0 or 512
  const int wm = (wave >> 1) << 5, wn = (wave & 1) << 5;
  const int qd = lane >> 4, md = lane & 15;
  const int sr = lane >> 2;
  const int sc = (lane & 3) << 3;

  float4v acc[2][2];
#pragma unroll
  for (int i = 0; i < 2; ++i)
#pragma unroll
    for (int j = 0; j < 2; ++j) acc[i][j] = (float4v)(0.f);

  for (int k0 = kb; k0 < kb + 512; k0 += 32) {
    const int row = wave * 16 + sr;
    async_ld16(&A [(size_t)(m0 + row) * NH + k0 + sc], &As[wave * 512]);
    async_ld16(&Bt[(size_t)(n0 + row) * NH + k0 + sc], &Bs[wave * 512]);
    __syncthreads();
    short8 af[2], bfr[2];
#pragma unroll
    for (int t = 0; t < 2; ++t) {
      af[t]  = *(const short8*)&As[(wm + t * 16 + md) * 32 + qd * 8];
      bfr[t] = *(const short8*)&Bs[(wn + t * 16 + md) * 32 + qd * 8];
    }
#pragma unroll
    for (int i = 0; i < 2; ++i)
#pragma unroll
      for (int j = 0; j < 2; ++j)
        acc[i][j] = __builtin_amdgcn_mfma_f32_16x16x32_bf16(bfr[j], af[i], acc[i][j], 0, 0, 0);
    __syncthreads();
  }

  float* out = Cpart + (size_t)blockIdx.z * NB * NH;
#pragma unroll
  for (int i = 0; i < 2; ++i) {
    const int rowg = m0 + wm + i * 16 + md;
#pragma unroll
    for (int j = 0; j < 2; ++j) {
      const int colb = n0 + wn + j * 16 + (qd << 2);
      float4 o;
      o.x = acc[i][j][0]; o.y = acc[i][j][1];
      o.z = acc[i][j][2]; o.w = acc[i][j][3];
      *reinterpret_cast<float4*>(&out[(size_t)rowg * NH + colb]) = o;
    }
  }
}

// ---------------- bf16 MFMA GEMM, 64x64 tile, fused backward epilogues (unsplit) ----------------
// FEPI 3 (bw1): t=acc*scale; ob=bf16(t*auxA), of1=sqrt(max(t*auxB,0))   [E1b, SD1]
// FEPI 4 (bw0): t=acc*scale; ob=bf16(t*auxA), of1=t*auxB               [GT0b, D0]
template<int FEPI>
__global__ __launch_bounds__(256) void k_mgemm64f(
    const short* __restrict__ A, const short* __restrict__ Bt,
    const float* __restrict__ auxA, const float* __restrict__ auxB,
    short* __restrict__ ob, float* __restrict__ of1,
    float scale)
{
  __shared__ short As[64 * 32];
  __shared__ short Bs[64 * 32];
  const int tid  = threadIdx.x;
  const int wave = tid >> 6, lane = tid & 63;
  const int m0 = blockIdx.x << 6, n0 = blockIdx.y << 6;
  const int wm = (wave >> 1) << 5, wn = (wave & 1) << 5;
  const int qd = lane >> 4, md = lane & 15;
  const int sr = lane >> 2;
  const int sc = (lane & 3) << 3;

  float4v acc[2][2];
#pragma unroll
  for (int i = 0; i < 2; ++i)
#pragma unroll
    for (int j = 0; j < 2; ++j) acc[i][j] = (float4v)(0.f);

  for (int k0 = 0; k0 < NH; k0 += 32) {
    const int row = wave * 16 + sr;
    async_ld16(&A [(size_t)(m0 + row) * NH + k0 + sc], &As[wave * 512]);
    async_ld16(&Bt[(size_t)(n0 + row) * NH + k0 + sc], &Bs[wave * 512]);
    __syncthreads();
    short8 af[2], bfr[2];
#pragma unroll
    for (int t = 0; t < 2; ++t) {
      af[t]  = *(const short8*)&As[(wm + t * 16 + md) * 32 + qd * 8];
      bfr[t] = *(const short8*)&Bs[(wn + t * 16 + md) * 32 + qd * 8];
    }
#pragma unroll
    for (int i = 0; i < 2; ++i)
#pragma unroll
      for (int j = 0; j < 2; ++j)
        acc[i][j] = __builtin_amdgcn_mfma_f32_16x16x32_bf16(bfr[j], af[i], acc[i][j], 0, 0, 0);
    __syncthreads();
  }

#pragma unroll
  for (int i = 0; i < 2; ++i) {
    const int rowg = m0 + wm + i * 16 + md;
#pragma unroll
    for (int j = 0; j < 2; ++j) {
      const int colb = n0 + wn + j * 16 + (qd << 2);
      const size_t oi = (size_t)rowg * NH + colb;
      const float4 g4 = *(const float4*)&auxA[oi];
      const float4 u4 = *(const float4*)&auxB[oi];
      const float gv[4] = {g4.x, g4.y, g4.z, g4.w};
      const float uv[4] = {u4.x, u4.y, u4.z, u4.w};
      short4v eb;
      float sd[4];
#pragma unroll
      for (int r = 0; r < 4; ++r) {
        const float t = acc[i][j][r] * scale;
        eb[r] = f2bf(t * gv[r]);
        if constexpr (FEPI == 3) sd[r] = sqrtf(fmaxf(t * uv[r], 0.f));
        else                     sd[r] = t * uv[r];
      }
      *(short4v*)&ob[oi] = eb;
      float4 s4; s4.x = sd[0]; s4.y = sd[1]; s4.z = sd[2]; s4.w = sd[3];
      *(float4*)&of1[oi] = s4;
    }
  }
}

// ---------------- activation (layer 1): sum HP halves, writes Zbf, G, U ----------------
__global__ __launch_bounds__(256) void k_act(
    const float* __restrict__ HP2, const float* __restrict__ HPC_l,
    const float* __restrict__ bA, const float* __restrict__ bB,
    const float* __restrict__ bC,
    const float* __restrict__ anb, const float* __restrict__ anl,
    short* __restrict__ Zbf, float* __restrict__ G, float* __restrict__ U,
    float scale)
{
  const int idx = blockIdx.x * 256 + threadIdx.x;
  const int i = idx & 1023;
  const float bias = bA[i] + bB[i] + bC[i] + anb[i];
  const float el = expf(anl[i]);
  const float hc = HPC_l[(size_t)(idx >> 10) * (3 * NH) + i];
  const float hp = (HP2[idx] + HP2[(size_t)NB * NH + idx]) * scale;
  const float a = (hp + hc + bias) * el;
  const float pdf = expf(-0.5f * a * a);
  const float er = erff(a * SQRT_HALF);
  Zbf[idx] = f2bf((SQRT_HPI * a * er + pdf + SQRT_HPI * a) * INV_SQRT2PI);
  G[idx] = 0.5f * (1.f + er) * el;
  U[idx] = pdf * INV_SQRT2PI * el * el;
}

// ---------------- activation (layer 2): SD2 = sqrt(t2*u2), D2g bf16 ----------------
__global__ __launch_bounds__(256) void k_act2(
    const float* __restrict__ HP2, const float* __restrict__ HPC_l,
    const float* __restrict__ bA, const float* __restrict__ bB,
    const float* __restrict__ bC,
    const float* __restrict__ anb, const float* __restrict__ anl,
    const float* __restrict__ so,
    float* __restrict__ SD2, short* __restrict__ D2gbf, float scale)
{
  const int idx = blockIdx.x * 256 + threadIdx.x;
  const int i = idx & 1023;
  const float bias = bA[i] + bB[i] + bC[i] + anb[i];
  const float el = expf(anl[i]);
  const float hc = HPC_l[(size_t)(idx >> 10) * (3 * NH) + i];
  const float hp = (HP2[idx] + HP2[(size_t)NB * NH + idx]) * scale;
  const float a = (hp + hc + bias) * el;
  const float pdf = expf(-0.5f * a * a);
  const float er = erff(a * SQRT_HALF);
  const float g = 0.5f * (1.f + er) * el;
  const float u = pdf * INV_SQRT2PI * el * el;
  const float t2 = so[i] * (1.f / NH);
  SD2[idx] = sqrtf(fmaxf(t2 * u, 0.f));
  D2gbf[idx] = f2bf(t2 * g);
}

// ---------------- Ah1[r,p] = bf16(G0[b,p] * W0T[j,p]) (coalesced) ----------------
__global__ __launch_bounds__(256) void k_scale0(
    const float* __restrict__ G0, const short* __restrict__ W0Tb,
    short* __restrict__ Ah1, int b0)
{
  const int idx = blockIdx.x * 256 + threadIdx.x;
  const int p = idx & 1023, r = idx >> 10;
  const int b = b0 + (r >> 5), j = r & 31;
  Ah1[idx] = f2bf(G0[(size_t)b * NH + p] * bf2f(W0Tb[(size_t)j * NH + p]));
}

// ---------------- f-GEMM: MFMA partials of [NB,NH]@[NH,32] per term/k-split ----------------
__global__ __launch_bounds__(256) void k_fgemm(
    const short* __restrict__ A0, const short* __restrict__ A1,
    const short* __restrict__ A2,
    const short* __restrict__ W0T, const short* __restrict__ W1T,
    const short* __restrict__ W2T,
    float* __restrict__ partF)
{
  const int mb = blockIdx.x;
  const int ks = blockIdx.y;
  const int term = blockIdx.z;
  const short* A  = (term == 0) ? A0 : (term == 1) ? A1 : A2;
  const short* WT = (term == 0) ? W0T : (term == 1) ? W1T : W2T;
  const int wave = threadIdx.x >> 6, lane = threadIdx.x & 63;
  const int qd = lane >> 4, md = lane & 15;
  const int m0 = mb * 128 + wave * 32;
  const int kbeg = ks * (NH / KSF);

  float4v acc[2][2];
#pragma unroll
  for (int i = 0; i < 2; ++i)
#pragma unroll
    for (int j = 0; j < 2; ++j) acc[i][j] = (float4v)(0.f);

  for (int k0 = kbeg; k0 < kbeg + NH / KSF; k0 += 32) {
    const int kk = k0 + qd * 8;
    short8 af[2], bfr[2];
    af[0]  = *(const short8*)&A[(size_t)(m0 + md) * NH + kk];
    af[1]  = *(const short8*)&A[(size_t)(m0 + 16 + md) * NH + kk];
    bfr[0] = *(const short8*)&WT[(size_t)md * NH + kk];
    bfr[1] = *(const short8*)&WT[(size_t)(16 + md) * NH + kk];
#pragma unroll
    for (int i = 0; i < 2; ++i)
#pragma unroll
      for (int j = 0; j < 2; ++j)
        acc[i][j] = __builtin_amdgcn_mfma_f32_16x16x32_bf16(af[i], bfr[j], acc[i][j], 0, 0, 0);
  }

  float* out = &partF[(size_t)(term * KSF + ks) * NB * 32];
#pragma unroll
  for (int i = 0; i < 2; ++i)
#pragma unroll
    for (int j = 0; j < 2; ++j)
#pragma unroll
      for (int r = 0; r < 4; ++r) {
        const int row = m0 + i * 16 + qd * 4 + r;
        const int col = j * 16 + md;
        out[(size_t)row * 32 + col] = acc[i][j][r];
      }
}

// ---------------- reduce f partials + epilogue ----------------
__global__ __launch_bounds__(256) void k_fred(
    const float* __restrict__ partF, const float* __restrict__ X,
    const float* __restrict__ Wxout,
    const float* __restrict__ w0p, const float* __restrict__ w1p,
    float* __restrict__ outF)
{
  const int e = blockIdx.x * 256 + threadIdx.x;
  float s = 0.f;
#pragma unroll
  for (int p = 0; p < 3 * KSF; ++p) s += partF[(size_t)p * NB * 32 + e];
  const float spw0 = sp_f(w0p[0]);
  const float spw1 = sp_f(w1p[0]);
  outF[e] = spw1 * (s + Wxout[e & 31]) + spw0 * X[e];
}

// ---------------- K-split per-sample Gram partials ----------------
__global__ __launch_bounds__(256) void k_gram(
    const short* __restrict__ Q1, const short* __restrict__ Q2,
    const short* __restrict__ W0T, const float* __restrict__ D0,
    float* __restrict__ partH, int b0)
{
  const int ns = blockIdx.x, bl = blockIdx.y;
  const int b = b0 + bl;
  const int wave = threadIdx.x >> 6, lane = threadIdx.x & 63;
  const int wm = (wave >> 1) << 4, wn = (wave & 1) << 4;
  const int qd = lane >> 4, md = lane & 15;
  const int kbeg = ns << 7;
  const size_t rb = (size_t)bl * 32 * NH;

  float4v acc = (float4v)(0.f);

  for (int k0 = kbeg; k0 < kbeg + 128; k0 += 32) {
    const int kk = k0 + qd * 8;
    const short8 ar = *(const short8*)&W0T[(size_t)(wm + md) * NH + kk];
    float dd[8];
    *(float4*)&dd[0] = *(const float4*)&D0[(size_t)b * NH + kk];
    *(float4*)&dd[4] = *(const float4*)&D0[(size_t)b * NH + kk + 4];
    short8 af;
#pragma unroll
    for (int e = 0; e < 8; ++e) af[e] = f2bf(bf2f(ar[e]) * dd[e]);
    const short8 bfr = *(const short8*)&W0T[(size_t)(wn + md) * NH + kk];
    acc = __builtin_amdgcn_mfma_f32_16x16x32_bf16(af, bfr, acc, 0, 0, 0);
  }
#pragma unroll
  for (int l = 0; l < 2; ++l) {
    const short* Q = (l == 0) ? Q1 : Q2;
    for (int k0 = kbeg; k0 < kbeg + 128; k0 += 32) {
      const int kk = k0 + qd * 8;
      const short8 af  = *(const short8*)&Q[rb + (size_t)(wm + md) * NH + kk];
      const short8 bfr = *(const short8*)&Q[rb + (size_t)(wn + md) * NH + kk];
      acc = __builtin_amdgcn_mfma_f32_16x16x32_bf16(af, bfr, acc, 0, 0, 0);
    }
  }

  float* out = &partH[((size_t)bl * NS + ns) * 1024];
#pragma unroll
  for (int r = 0; r < 4; ++r)
    out[(wm + qd * 4 + r) * 32 + (wn + md)] = acc[r];
}

// ---------------- reduce partials + Cholesky logdet ----------------
__global__ __launch_bounds__(256) void k_gram2(
    const float* __restrict__ partH,
    const float* __restrict__ w0p, const float* __restrict__ w1p,
    float* __restrict__ outLD, int b0)
{
  const int bl = blockIdx.x, b = b0 + bl, tid = threadIdx.x;
  __shared__ float sH[32][33];
  __shared__ float sred[32];
  const float spw0 = sp_f(w0p[0]);
  const float spw1 = sp_f(w1p[0]);
  const float* base = &partH[(size_t)bl * NS * 1024];
#pragma unroll
  for (int r = 0; r < 4; ++r) {
    const int e = r * 256 + tid;
    float s = 0.f;
#pragma unroll
    for (int ns = 0; ns < NS; ++ns) s += base[ns * 1024 + e];
    float h = s * spw1;
    const int row = e >> 5, col = e & 31;
    if (row == col) h += spw0;
    sH[row][col] = h;
  }
  __syncthreads();

  float ldacc = 0.f;
  for (int c = 0; c < 32; ++c) {
    if (tid >= c && tid < 32) {
      float s = sH[tid][c];
      for (int m = 0; m < c; ++m) s -= sH[tid][m] * sH[c][m];
      sred[tid] = s;
    }
    __syncthreads();
    const float sc = sred[c];
    if (tid >= c && tid < 32) {
      const float lcc = sqrtf(sc);
      sH[tid][c] = (tid == c) ? lcc : sred[tid] / lcc;
    }
    ldacc += logf(sc);
    __syncthreads();
  }
  if (tid == 0) outLD[b] = ldacc;
}

// ---------------- launcher ----------------
extern "C" void kernel_launch(void* const* d_in, const int* in_sizes, int n_in,
                              void* d_out, int out_size, void* d_ws, size_t ws_size,
                              hipStream_t stream)
{
  const float* X    = (const float*)d_in[0];
  const float* Cc   = (const float*)d_in[1];
  const float* w0   = (const float*)d_in[2];
  const float* w1   = (const float*)d_in[3];
  const float* Wz0w = (const float*)d_in[4];
  const float* Wz0b = (const float*)d_in[5];
  const float* Wc0w = (const float*)d_in[6];
  const float* Wc0b = (const float*)d_in[7];
  const float* an0b = (const float*)d_in[8];
  const float* an0l = (const float*)d_in[9];
  const float* Wz1w = (const float*)d_in[10];
  const float* Wz1b = (const float*)d_in[11];
  const float* Wx1w = (const float*)d_in[12];
  const float* Wx1b = (const float*)d_in[13];
  const float* Wc1w = (const float*)d_in[14];
  const float* Wc1b = (const float*)d_in[15];
  const float* an1b = (const float*)d_in[16];
  const float* an1l = (const float*)d_in[17];
  const float* Wz2w = (const float*)d_in[18];
  const float* Wz2b = (const float*)d_in[19];
  const float* Wx2w = (const float*)d_in[20];
  const float* Wx2b = (const float*)d_in[21];
  const float* Wc2w = (const float*)d_in[22];
  const float* Wc2b = (const float*)d_in[23];
  const float* an2b = (const float*)d_in[24];
  const float* an2l = (const float*)d_in[25];
  const float* Wzoutw = (const float*)d_in[26];
  const float* Wxoutw = (const float*)d_in[27];
  // d_in[28] (Wcout_w): constant in x -> no grad/Hessian contribution.

  float* ws = (float*)d_ws;
  size_t off = 0;
  auto alloc = [&](size_t n) {
    float* p = ws + off; off += (n + 3) & ~(size_t)3; return p;
  };
  const size_t HH = (size_t)NH * NH;
  const size_t BH = (size_t)NB * NH;

  short* S1b  = (short*)alloc(HH / 2);
  short* S2b  = (short*)alloc(HH / 2);
  short* S1Tb = (short*)alloc(HH / 2);
  short* S2Tb = (short*)alloc(HH / 2);
  short* Wc0bb = (short*)alloc((size_t)NH * NC / 2);
  short* Wc1bb = (short*)alloc((size_t)NH * NC / 2);
  short* Wc2bb = (short*)alloc((size_t)NH * NC / 2);
  short* Ccb  = (short*)alloc((size_t)NB * NC / 2);
  short* W0Tb = (short*)alloc((size_t)NDIM * NH / 2);
  short* Wx1Tb = (short*)alloc((size_t)NDIM * NH / 2);
  short* Wx2Tb = (short*)alloc((size_t)NDIM * NH / 2);
  float* so   = alloc(NH);
  float* HP2  = alloc(2 * BH);                // K-split GEMM partials
  float* HPC  = alloc((size_t)NB * 3 * NH);   // c-path + X-terms [NB, 3*NH]
  short* Z0b  = (short*)alloc(BH / 2);
  short* Z1b  = (short*)alloc(BH / 2);
  float* G0   = alloc(BH);
  float* U0   = alloc(BH);
  float* G1   = alloc(BH);
  float* U1   = alloc(BH);
  float* SD2  = alloc(BH);
  short* D2gb = (short*)alloc(BH / 2);
  short* E1b  = (short*)alloc(BH / 2);
  float* SD1  = alloc(BH);
  float* D0   = alloc(BH);
  short* GT0b = (short*)alloc(BH / 2);
  float* partF = alloc((size_t)3 * KSF * NB * 32);

  // chunk buffers: Ah1, A2, Q1 (bf16); Q2 aliases Ah1 (dead after GEMM1)
  const size_t avail_f = ws_size / sizeof(float);
  int CB = 32;
  const int cands[6] = {1024, 512, 256, 128, 64, 32};
  for (int ci = 0; ci < 6; ++ci) {
    const size_t need = off + 3 * ((size_t)cands[ci] * 32 * NH / 2 + 4)
                      + (size_t)cands[ci] * NS * 1024 + 64;
    if (need <= avail_f) { CB = cands[ci]; break; }
  }
  const size_t chunk_sh = (size_t)CB * 32 * NH;
  short* Ah1 = (short*)alloc(chunk_sh / 2);
  short* A2b = (short*)alloc(chunk_sh / 2);
  short* Q1b = (short*)alloc(chunk_sh / 2);
  short* Q2b = Ah1;
  float* partH = alloc((size_t)CB * NS * 1024);

  float* outF  = (float*)d_out;
  float* outLD = (float*)d_out + NB * NDIM;

  const dim3 blk2(16, 16);
  const dim3 gridXz(16, NB / 64, 3);        // fused X-terms (+ act0 in z=0)
  const dim3 gridE(NB * NH / 256);
  const dim3 grid64s(NB / 64, NH / 64, 2);  // K-split 64-tile mfma (512 blocks)
  const dim3 grid64u(NB / 64, NH / 64);     // unsplit fused-backward 64-tile
  const dim3 gridC(NB / 128, 3 * NH / 128); // fused c-GEMM
  const float invH = 1.0f / (float)NH;

  k_prep<<<dim3(HH / 256), dim3(256), 0, stream>>>(
      Wz1w, Wz2w, Wzoutw, Wz0w, Wx1w, Wx2w, Wc0w, Wc1w, Wc2w, Cc,
      S1b, S1Tb, S2b, S2Tb, Wc0bb, Wc1bb, Wc2bb, Ccb, W0Tb, Wx1Tb, Wx2Tb, so);

  // HPC = c-path (bf16 MFMA), then X-terms (fp32) with fused layer-0 activation (z=0)
  k_m128<<<gridC, dim3(256), 0, stream>>>(Ccb, Wc0bb, HPC, 1.f, NC, 3 * NH);
  k_gemmx<<<gridXz, blk2, 0, stream>>>(X, Wz0w, Wx1w, Wx2w,
                                       HPC + 0 * NH, HPC + 1 * NH, HPC + 2 * NH, 3 * NH,
                                       Wz0b, Wc0b, an0b, an0l, Z0b, G0, U0);

  // layer 1
  k_mgemm64s<<<grid64s, dim3(256), 0, stream>>>(Z0b, S1b, HP2);
  k_act<<<gridE, dim3(256), 0, stream>>>(HP2, HPC + 1 * NH, Wz1b, Wx1b, Wc1b,
                                         an1b, an1l, Z1b, G1, U1, invH);
  // layer 2
  k_mgemm64s<<<grid64s, dim3(256), 0, stream>>>(Z1b, S2b, HP2);
  k_act2<<<gridE, dim3(256), 0, stream>>>(HP2, HPC + 2 * NH, Wz2b, Wx2b, Wc2b,
                                          an2b, an2l, so, SD2, D2gb, invH);
  // backward sensitivities (fused epilogues, unsplit)
  k_mgemm64f<3><<<grid64u, dim3(256), 0, stream>>>(D2gb, S2Tb, G1, U1, E1b, SD1, invH);
  k_mgemm64f<4><<<grid64u, dim3(256), 0, stream>>>(E1b, S1Tb, G0, U0, GT0b, D0, invH);

  // f (grad) via MFMA partials + reduce
  k_fgemm<<<dim3(8, KSF, 3), dim3(256), 0, stream>>>(
      GT0b, E1b, D2gb, W0Tb, Wx1Tb, Wx2Tb, partF);
  k_fred<<<dim3(NB * 32 / 256), dim3(256), 0, stream>>>(
      partF, X, Wxoutw, w0, w1, outF);

  // Jacobian propagation + K-split Gram + Cholesky, chunked over samples
  const dim3 gridJ(CB * 32 / 128, NH / 64);    // 128x64 tile (x = M-block, XCD swizzle)
  const dim3 gridS((size_t)CB * 32 * NH / 256);
  const dim3 gridG(NS, CB);
  for (int b0 = 0; b0 < NB; b0 += CB) {
    k_scale0<<<gridS, dim3(256), 0, stream>>>(G0, W0Tb, Ah1, b0);
    k_mgemm<2><<<gridJ, dim3(256), 0, stream>>>(Ah1, S1b, Q1b, A2b,
                                                G1, SD1, Wx1Tb, invH, NH, b0);
    k_mgemm<1><<<gridJ, dim3(256), 0, stream>>>(A2b, S2b, Q2b, nullptr,
                                                nullptr, SD2, Wx2Tb, invH, NH, b0);
    k_gram<<<gridG, dim3(256), 0, stream>>>(Q1b, Q2b, W0Tb, D0, partH, b0);
    k_gram2<<<dim3(CB), dim3(256), 0, stream>>>(partH, w0, w1, outLD, b0);
  }
}